// Round 11
// baseline (258.818 us; speedup 1.0000x reference)
//
#include <hip/hip_runtime.h>

#define E_DIM 69120
#define N1 60
#define H 32
#define CC 3
#define TEB 64
#define NB2 (E_DIM / TEB)   // 1080
#define SDS 68              // d-tile stride (floats)
#define SBA 34              // chain buffer stride (floats, 8B-aligned rows)
#define SBT 68              // bufT stride (16B-aligned rows for b128)
#define PSZ (N1 * H)        // 1920

typedef float f2 __attribute__((ext_vector_type(2)));

__device__ __forceinline__ f2 relu_fma2(f2 a, f2 b, f2 c) {
    return __builtin_elementwise_max(__builtin_elementwise_fma(a, b, c), (f2)(0.f));
}
__device__ __forceinline__ float relu_dot4(const float4 d, const float w, const float4 t) {
    return fmaxf(fmaf(d.x, w, t.x), 0.f) + fmaxf(fmaf(d.y, w, t.y), 0.f)
         + fmaxf(fmaf(d.z, w, t.z), 0.f) + fmaxf(fmaf(d.w, w, t.w), 0.f);
}

// LDS: ds[60*68]=4080f | bufAT[2176]f ([64][34] chain / [32][68] bufT overlay)
//      | bufB[64*34]=2176f  -> 8432 f = 33728 B -> 4 blocks/CU

// =====================================================================
// kA15: v_bar chain + alpha atomic accumulation.
// =====================================================================
__global__ __launch_bounds__(512, 4) void kA15(
    const float* __restrict__ d,
    const float* __restrict__ Wfvb, const float* __restrict__ bfvb,
    const float* __restrict__ Wgvb, const float* __restrict__ bgvb,
    const float* __restrict__ Wfu,  const float* __restrict__ bfu,
    float* __restrict__ alphaAcc)
{
    __shared__ __align__(16) float ds[N1 * SDS];
    __shared__ __align__(16) float bufAT[2176];
    __shared__ __align__(16) float bufB[2176];
    const int tid = threadIdx.x;
    const long sE = (long)blockIdx.x * TEB;

    // ph0: stage support tile
    for (int i = tid; i < N1 * (TEB / 4); i += 512) {
        const int n = i >> 4, c = (i & 15) * 4;
        *(float4*)(ds + n * SDS + c) = *(const float4*)(d + (long)n * E_DIM + sE + c);
    }
    __syncthreads();

    const int eL = tid & 63;
    const int h0 = __builtin_amdgcn_readfirstlane((tid >> 6) * 4);

    // ph1: t1 = mean_n relu(d*wf + bf); packed, dual accumulators, 1/N1 folded
    {
        f2 wf[2], bf[2], ta[2], tb[2];
        #pragma unroll
        for (int q = 0; q < 2; ++q) {
            wf[q] = f2{Wfvb[h0 + 2*q] * (1.f/N1), Wfvb[h0 + 2*q + 1] * (1.f/N1)};
            bf[q] = f2{bfvb[h0 + 2*q] * (1.f/N1), bfvb[h0 + 2*q + 1] * (1.f/N1)};
            ta[q] = (f2)(0.f); tb[q] = (f2)(0.f);
        }
        const float* dp = ds + eL;
        #pragma unroll 5
        for (int n = 0; n < N1; n += 2) {
            const float dv0 = dp[n * SDS];
            const float dv1 = dp[(n + 1) * SDS];
            const f2 dv02 = f2{dv0, dv0}, dv12 = f2{dv1, dv1};
            #pragma unroll
            for (int q = 0; q < 2; ++q) {
                ta[q] += relu_fma2(dv02, wf[q], bf[q]);
                tb[q] += relu_fma2(dv12, wf[q], bf[q]);
            }
        }
        #pragma unroll
        for (int q = 0; q < 2; ++q)
            *(f2*)(bufAT + eL * SBA + h0 + 2*q) = ta[q] + tb[q];
    }
    __syncthreads();

    // ph2: vb = relu(t1 @ Wgvb + bgvb) -> bufB (packed)
    {
        f2 acc[2];
        #pragma unroll
        for (int q = 0; q < 2; ++q) acc[q] = f2{bgvb[h0 + 2*q], bgvb[h0 + 2*q + 1]};
        #pragma unroll
        for (int k = 0; k < H; ++k) {
            const float t = bufAT[eL * SBA + k];
            const f2 t2 = f2{t, t};
            #pragma unroll
            for (int q = 0; q < 2; ++q)
                acc[q] = __builtin_elementwise_fma(t2, *(const f2*)(Wgvb + k * H + h0 + 2*q), acc[q]);
        }
        #pragma unroll
        for (int q = 0; q < 2; ++q)
            *(f2*)(bufB + eL * SBA + h0 + 2*q) = __builtin_elementwise_max(acc[q], (f2)(0.f));
    }
    __syncthreads();

    // ph3: vw = vb @ Wu_v + b_fu -> bufT (transposed; bufAT dead)
    {
        f2 acc[2];
        #pragma unroll
        for (int q = 0; q < 2; ++q) acc[q] = f2{bfu[h0 + 2*q], bfu[h0 + 2*q + 1]};
        #pragma unroll
        for (int k = 0; k < H; ++k) {
            const float t = bufB[eL * SBA + k];
            const f2 t2 = f2{t, t};
            #pragma unroll
            for (int q = 0; q < 2; ++q)
                acc[q] = __builtin_elementwise_fma(t2, *(const f2*)(Wfu + k * H + h0 + 2*q), acc[q]);
        }
        #pragma unroll
        for (int q = 0; q < 2; ++q) {
            bufAT[(h0 + 2*q)     * SBT + eL] = acc[q].x;
            bufAT[(h0 + 2*q + 1) * SBT + eL] = acc[q].y;
        }
    }
    __syncthreads();

    // ph4: alpha; thread = (np 0..29 -> 2n, hg 0..7 -> 4h). w shared across n-pair.
    if (tid < (N1 / 2) * 8) {
        const int np = tid >> 3, hb = (tid & 7) * 4;
        const int n0 = 2 * np, n1 = n0 + 1;
        float wud[4], a0[4], a1[4];
        #pragma unroll
        for (int j = 0; j < 4; ++j) { wud[j] = Wfu[H * H + hb + j]; a0[j] = 0.f; a1[j] = 0.f; }
        const float* r0 = ds + n0 * SDS;
        const float* r1 = ds + n1 * SDS;
        for (int e8 = 0; e8 < TEB; e8 += 8) {
            const float4 d0a = *(const float4*)(r0 + e8);
            const float4 d0b = *(const float4*)(r0 + e8 + 4);
            const float4 d1a = *(const float4*)(r1 + e8);
            const float4 d1b = *(const float4*)(r1 + e8 + 4);
            #pragma unroll
            for (int j = 0; j < 4; ++j) {
                const float* wr = bufAT + (hb + j) * SBT + e8;
                const float4 wA = *(const float4*)(wr);
                const float4 wB = *(const float4*)(wr + 4);
                a0[j] += relu_dot4(d0a, wud[j], wA) + relu_dot4(d0b, wud[j], wB);
                a1[j] += relu_dot4(d1a, wud[j], wA) + relu_dot4(d1b, wud[j], wB);
            }
        }
        float* p0 = alphaAcc + n0 * H + hb;
        float* p1 = alphaAcc + n1 * H + hb;
        #pragma unroll
        for (int j = 0; j < 4; ++j) { atomicAdd(&p0[j], a0[j]); atomicAdd(&p1[j], a1[j]); }
    }
}

// =====================================================================
// kCf15: inline-kB + fused v-chain + z atomic accumulation.
// =====================================================================
__global__ __launch_bounds__(512, 4) void kCf15(
    const float* __restrict__ d, const float* __restrict__ d2,
    const float* __restrict__ alphaAcc, const int* __restrict__ label,
    const float* __restrict__ Wfvb, const float* __restrict__ bfvb,
    const float* __restrict__ Wgvb, const float* __restrict__ bgvb,
    const float* __restrict__ Wfu,  const float* __restrict__ bfu,
    const float* __restrict__ Wgu,  const float* __restrict__ bgu,
    const float* __restrict__ Wfvc, const float* __restrict__ bfvc,
    const float* __restrict__ Wgvc, const float* __restrict__ bgvc,
    const float* __restrict__ Wfz,  const float* __restrict__ bfz,
    float* __restrict__ zAcc)
{
    __shared__ __align__(16) float ds[N1 * SDS];
    __shared__ __align__(16) float bufAT[2176];
    __shared__ __align__(16) float bufB[2176];   // u_l lives here until ph2
    __shared__ int cnt[CC];
    const int tid = threadIdx.x;
    const long sE = (long)blockIdx.x * TEB;

    // ph0: stage support tile
    for (int i = tid; i < N1 * (TEB / 4); i += 512) {
        const int n = i >> 4, c = (i & 15) * 4;
        *(float4*)(ds + n * SDS + c) = *(const float4*)(d + (long)n * E_DIM + sE + c);
    }

    // ---- inline kB -> u_l (= bufB), scaled by 1/N1 ----
    float* up = bufAT;            // 1920
    float* cb = bufAT + 1920;     // 96
    float* cw = bufAT + 2016;     // 96  (2112 <= 2176)
    float* un = bufB;             // 1920

    if (tid < CC) cnt[tid] = 0;
    __syncthreads();
    if (tid < N1) atomicAdd(&cnt[label[tid]], 1);
    __syncthreads();
    if (tid < CC * H) {
        const int c = tid / H, h = tid % H;
        const float nc = (float)cnt[c];
        float s = bgvb[h];
        #pragma unroll
        for (int k = 0; k < H; ++k) {
            const float t1c = (nc * fmaxf(Wfvb[k] + bfvb[k], 0.f) +
                               ((float)N1 - nc) * fmaxf(bfvb[k], 0.f)) * (1.f / N1);
            s = fmaf(t1c, Wgvb[k * H + h], s);
        }
        cb[tid] = fmaxf(s, 0.f);
    }
    __syncthreads();
    if (tid < CC * H) {
        const int c = tid / H, h = tid % H;
        float s = bfu[h];
        #pragma unroll
        for (int k = 0; k < H; ++k) s = fmaf(cb[c * H + k], Wfu[k * H + h], s);
        cw[tid] = s;
    }
    __syncthreads();
    for (int t = tid; t < PSZ; t += 512) {
        const int n = t >> 5, h = t & 31;
        const int ln = label[n];
        const float wud = Wfu[H * H + h];
        float s = 0.f;
        #pragma unroll
        for (int c = 0; c < CC; ++c)
            s += fmaxf(cw[c * H + h] + ((c == ln) ? wud : 0.f), 0.f);
        up[t] = alphaAcc[t] * (1.f / E_DIM) + s * (1.f / CC);
    }
    __syncthreads();
    for (int t = tid; t < PSZ; t += 512) {
        const int n = t >> 5, h = t & 31;
        float s = bgu[h];
        #pragma unroll
        for (int k = 0; k < H; ++k) s = fmaf(up[n * H + k], Wgu[k * H + h], s);
        un[t] = fmaxf(s, 0.f);
    }
    __syncthreads();
    {   // uwb = (un @ Wv_u + b_fvc) * (1/N1), in-place in bufB (two-pass)
        float vv[4];
        int m = 0;
        for (int t = tid; t < PSZ; t += 512, ++m) {
            const int n = t >> 5, h = t & 31;
            float s = bfvc[h];
            #pragma unroll
            for (int k = 0; k < H; ++k) s = fmaf(un[n * H + k], Wfvc[k * H + h], s);
            vv[m] = s * (1.f / N1);
        }
        __syncthreads();
        m = 0;
        for (int t = tid; t < PSZ; t += 512, ++m) bufB[t] = vv[m];
    }
    __syncthreads();

    const int eL = tid & 63;
    const int h0 = __builtin_amdgcn_readfirstlane((tid >> 6) * 4);

    // ph1: m = mean_n relu(d*wvd + u); packed, dual-n; scales folded
    {
        f2 wvd[2], ma[2], mb[2];
        #pragma unroll
        for (int q = 0; q < 2; ++q) {
            wvd[q] = f2{Wfvc[H * H + h0 + 2*q] * (1.f/N1), Wfvc[H * H + h0 + 2*q + 1] * (1.f/N1)};
            ma[q] = (f2)(0.f); mb[q] = (f2)(0.f);
        }
        const float* dp = ds + eL;
        #pragma unroll 5
        for (int n = 0; n < N1; n += 2) {
            const float dv0 = dp[n * SDS];
            const float dv1 = dp[(n + 1) * SDS];
            const f2 dv02 = f2{dv0, dv0}, dv12 = f2{dv1, dv1};
            #pragma unroll
            for (int q = 0; q < 2; ++q) {
                const f2 u0 = *(const f2*)(bufB + n * H + h0 + 2*q);
                const f2 u1 = *(const f2*)(bufB + (n + 1) * H + h0 + 2*q);
                ma[q] += relu_fma2(dv02, wvd[q], u0);
                mb[q] += relu_fma2(dv12, wvd[q], u1);
            }
        }
        #pragma unroll
        for (int q = 0; q < 2; ++q)
            *(f2*)(bufAT + eL * SBA + h0 + 2*q) = ma[q] + mb[q];
    }
    __syncthreads();

    // ph2: v = relu(m @ Wgvc + bgvc) -> bufB (u_l dead)
    {
        f2 acc[2];
        #pragma unroll
        for (int q = 0; q < 2; ++q) acc[q] = f2{bgvc[h0 + 2*q], bgvc[h0 + 2*q + 1]};
        #pragma unroll
        for (int k = 0; k < H; ++k) {
            const float t = bufAT[eL * SBA + k];
            const f2 t2 = f2{t, t};
            #pragma unroll
            for (int q = 0; q < 2; ++q)
                acc[q] = __builtin_elementwise_fma(t2, *(const f2*)(Wgvc + k * H + h0 + 2*q), acc[q]);
        }
        #pragma unroll
        for (int q = 0; q < 2; ++q)
            *(f2*)(bufB + eL * SBA + h0 + 2*q) = __builtin_elementwise_max(acc[q], (f2)(0.f));
    }
    __syncthreads();

    // ph3: vz = v @ Wz_v + b_fz -> bufT
    {
        f2 acc[2];
        #pragma unroll
        for (int q = 0; q < 2; ++q) acc[q] = f2{bfz[h0 + 2*q], bfz[h0 + 2*q + 1]};
        #pragma unroll
        for (int k = 0; k < H; ++k) {
            const float t = bufB[eL * SBA + k];
            const f2 t2 = f2{t, t};
            #pragma unroll
            for (int q = 0; q < 2; ++q)
                acc[q] = __builtin_elementwise_fma(t2, *(const f2*)(Wfz + k * H + h0 + 2*q), acc[q]);
        }
        #pragma unroll
        for (int q = 0; q < 2; ++q) {
            bufAT[(h0 + 2*q)     * SBT + eL] = acc[q].x;
            bufAT[(h0 + 2*q + 1) * SBT + eL] = acc[q].y;
        }
    }
    __syncthreads();

    // ph4: z; query rows from global (first touch), vz from LDS, n-paired
    if (tid < (N1 / 2) * 8) {
        const int np = tid >> 3, hb = (tid & 7) * 4;
        const int n0 = 2 * np, n1 = n0 + 1;
        float wzd[4], a0[4], a1[4];
        #pragma unroll
        for (int j = 0; j < 4; ++j) { wzd[j] = Wfz[H * H + hb + j]; a0[j] = 0.f; a1[j] = 0.f; }
        const float* r0 = d2 + (long)n0 * E_DIM + sE;
        const float* r1 = d2 + (long)n1 * E_DIM + sE;
        for (int e8 = 0; e8 < TEB; e8 += 8) {
            const float4 d0a = *(const float4*)(r0 + e8);
            const float4 d0b = *(const float4*)(r0 + e8 + 4);
            const float4 d1a = *(const float4*)(r1 + e8);
            const float4 d1b = *(const float4*)(r1 + e8 + 4);
            #pragma unroll
            for (int j = 0; j < 4; ++j) {
                const float* wr = bufAT + (hb + j) * SBT + e8;
                const float4 wA = *(const float4*)(wr);
                const float4 wB = *(const float4*)(wr + 4);
                a0[j] += relu_dot4(d0a, wzd[j], wA) + relu_dot4(d0b, wzd[j], wB);
                a1[j] += relu_dot4(d1a, wzd[j], wA) + relu_dot4(d1b, wzd[j], wB);
            }
        }
        float* p0 = zAcc + n0 * H + hb;
        float* p1 = zAcc + n1 * H + hb;
        #pragma unroll
        for (int j = 0; j < 4; ++j) { atomicAdd(&p0[j], a0[j]); atomicAdd(&p1[j], a1[j]); }
    }
}

// ---------------- kD: output ----------------
__global__ __launch_bounds__(1024) void kD(
    const float* __restrict__ zAcc,
    const float* __restrict__ Wgz, const float* __restrict__ bgz,
    float* __restrict__ out)
{
    __shared__ float z_l[N1 * H];
    const int tid = threadIdx.x;
    for (int t = tid; t < N1 * H; t += 1024) z_l[t] = zAcc[t] * (1.f / E_DIM);
    __syncthreads();
    for (int t = tid; t < N1 * H; t += 1024) {
        const int n = t >> 5, h = t & 31;
        float s = bgz[h];
        #pragma unroll
        for (int k = 0; k < H; ++k) s = fmaf(z_l[n * H + k], Wgz[k * H + h], s);
        out[t] = fmaxf(s, 0.f);
    }
}

extern "C" void kernel_launch(void* const* d_in, const int* in_sizes, int n_in,
                              void* d_out, int out_size, void* d_ws, size_t ws_size,
                              hipStream_t stream)
{
    const float* sup  = (const float*)d_in[0];
    const int*   lab  = (const int*)d_in[1];
    const float* qry  = (const float*)d_in[2];
    const float* Wfvb = (const float*)d_in[3];
    const float* bfvb = (const float*)d_in[4];
    const float* Wgvb = (const float*)d_in[5];
    const float* bgvb = (const float*)d_in[6];
    const float* Wfu  = (const float*)d_in[7];
    const float* bfu  = (const float*)d_in[8];
    const float* Wgu  = (const float*)d_in[9];
    const float* bgu  = (const float*)d_in[10];
    const float* Wfvc = (const float*)d_in[11];
    const float* bfvc = (const float*)d_in[12];
    const float* Wgvc = (const float*)d_in[13];
    const float* bgvc = (const float*)d_in[14];
    const float* Wfz  = (const float*)d_in[15];
    const float* bfz  = (const float*)d_in[16];
    const float* Wgz  = (const float*)d_in[17];
    const float* bgz  = (const float*)d_in[18];
    float* out = (float*)d_out;

    float* alphaAcc = (float*)d_ws;          // PSZ
    float* zAcc     = alphaAcc + PSZ;        // PSZ

    (void)hipMemsetAsync(alphaAcc, 0, 2 * PSZ * sizeof(float), stream);

    kA15<<<NB2, 512, 0, stream>>>(sup, Wfvb, bfvb, Wgvb, bgvb, Wfu, bfu, alphaAcc);
    kCf15<<<NB2, 512, 0, stream>>>(sup, qry, alphaAcc, lab,
                                   Wfvb, bfvb, Wgvb, bgvb, Wfu, bfu,
                                   Wgu, bgu, Wfvc, bfvc, Wgvc, bgvc,
                                   Wfz, bfz, zAcc);
    kD<<<1, 1024, 0, stream>>>(zAcc, Wgz, bgz, out);
}

// Round 12
// 106.875 us; speedup vs baseline: 2.4217x; 2.4217x over previous
//
#include <hip/hip_runtime.h>

#define E_DIM 69120
#define N1 60
#define H 32
#define CC 3
#define TEB 128
#define NB2 (E_DIM / TEB)   // 540
#define SDS 132             // d-tile stride (floats); rows 16B-aligned, 2-way banks
#define SBA 34              // chain buffer stride
#define SBT 132             // bufT stride (16B-aligned rows for b128)
#define PSZ (N1 * H)        // 1920

__device__ __forceinline__ float relu_dot4(const float4 d, const float w, const float4 t) {
    return fmaxf(fmaf(d.x, w, t.x), 0.f) + fmaxf(fmaf(d.y, w, t.y), 0.f)
         + fmaxf(fmaf(d.z, w, t.z), 0.f) + fmaxf(fmaf(d.w, w, t.w), 0.f);
}

// LDS: ds[60*132]=7920f | bufAT[4352]f ([128][34] chain / [32][132] bufT overlay)
//      | bufB[4352]f ([128][34]; u_l[60][32] overlay in kCf)
// total 16,624 f = 66,496 B -> 2 blocks/CU x 8 waves

// =====================================================================
// kA17: v_bar chain + alpha partials. 512 thr; thread owns e=eL and e=eL+64.
// =====================================================================
template<bool ATOMIC>
__global__ __launch_bounds__(512, 4) void kA17(
    const float* __restrict__ d,
    const float* __restrict__ Wfvb, const float* __restrict__ bfvb,
    const float* __restrict__ Wgvb, const float* __restrict__ bgvb,
    const float* __restrict__ Wfu,  const float* __restrict__ bfu,
    float* __restrict__ outp)
{
    __shared__ __align__(16) float ds[N1 * SDS];
    __shared__ __align__(16) float bufAT[4352];
    __shared__ __align__(16) float bufB[4352];
    const int tid = threadIdx.x;
    const long sE = (long)blockIdx.x * TEB;

    // ph0: stage support tile
    for (int i = tid; i < N1 * (TEB / 4); i += 512) {
        const int n = i >> 5, c = (i & 31) * 4;
        *(float4*)(ds + n * SDS + c) = *(const float4*)(d + (long)n * E_DIM + sE + c);
    }
    __syncthreads();

    const int eL = tid & 63;
    const int h0 = __builtin_amdgcn_readfirstlane((tid >> 6) * 4);

    // ph1: t1 = mean_n relu(d*wf + bf) for two e's; dual-n acc; 1/N1 folded
    {
        float wf[4], bf[4], tA0[4], tA1[4], tB0[4], tB1[4];
        #pragma unroll
        for (int j = 0; j < 4; ++j) {
            wf[j] = Wfvb[h0 + j] * (1.f / N1);
            bf[j] = bfvb[h0 + j] * (1.f / N1);
            tA0[j] = 0.f; tA1[j] = 0.f; tB0[j] = 0.f; tB1[j] = 0.f;
        }
        const float* dp0 = ds + eL;
        const float* dp1 = ds + eL + 64;
        #pragma unroll 5
        for (int n = 0; n < N1; n += 2) {
            const float a0 = dp0[n * SDS],       a1 = dp1[n * SDS];
            const float b0 = dp0[(n + 1) * SDS], b1 = dp1[(n + 1) * SDS];
            #pragma unroll
            for (int j = 0; j < 4; ++j) {
                tA0[j] += fmaxf(fmaf(a0, wf[j], bf[j]), 0.f);
                tA1[j] += fmaxf(fmaf(a1, wf[j], bf[j]), 0.f);
                tB0[j] += fmaxf(fmaf(b0, wf[j], bf[j]), 0.f);
                tB1[j] += fmaxf(fmaf(b1, wf[j], bf[j]), 0.f);
            }
        }
        #pragma unroll
        for (int j = 0; j < 4; ++j) {
            bufAT[eL * SBA + h0 + j]        = tA0[j] + tB0[j];
            bufAT[(eL + 64) * SBA + h0 + j] = tA1[j] + tB1[j];
        }
    }
    __syncthreads();

    // ph2: vb = relu(t1 @ Wgvb + bgvb) -> bufB, both e-rows
    {
        float a0[4], a1[4];
        #pragma unroll
        for (int j = 0; j < 4; ++j) { a0[j] = bgvb[h0 + j]; a1[j] = a0[j]; }
        #pragma unroll
        for (int k = 0; k < H; ++k) {
            const float t0 = bufAT[eL * SBA + k];
            const float t1 = bufAT[(eL + 64) * SBA + k];
            #pragma unroll
            for (int j = 0; j < 4; ++j) {
                const float w = Wgvb[k * H + h0 + j];
                a0[j] = fmaf(t0, w, a0[j]);
                a1[j] = fmaf(t1, w, a1[j]);
            }
        }
        #pragma unroll
        for (int j = 0; j < 4; ++j) {
            bufB[eL * SBA + h0 + j]        = fmaxf(a0[j], 0.f);
            bufB[(eL + 64) * SBA + h0 + j] = fmaxf(a1[j], 0.f);
        }
    }
    __syncthreads();

    // ph3: vw = vb @ Wu_v + b_fu -> bufT (transposed; chain region dead)
    {
        float a0[4], a1[4];
        #pragma unroll
        for (int j = 0; j < 4; ++j) { a0[j] = bfu[h0 + j]; a1[j] = a0[j]; }
        #pragma unroll
        for (int k = 0; k < H; ++k) {
            const float t0 = bufB[eL * SBA + k];
            const float t1 = bufB[(eL + 64) * SBA + k];
            #pragma unroll
            for (int j = 0; j < 4; ++j) {
                const float w = Wfu[k * H + h0 + j];
                a0[j] = fmaf(t0, w, a0[j]);
                a1[j] = fmaf(t1, w, a1[j]);
            }
        }
        #pragma unroll
        for (int j = 0; j < 4; ++j) {
            bufAT[(h0 + j) * SBT + eL]      = a0[j];
            bufAT[(h0 + j) * SBT + eL + 64] = a1[j];
        }
    }
    __syncthreads();

    // ph4: alpha partials; thread = (np -> 2n, hg -> 4h), 240 active
    if (tid < (N1 / 2) * 8) {
        const int np = tid >> 3, hb = (tid & 7) * 4;
        const int n0 = 2 * np, n1 = n0 + 1;
        float wud[4], a0[4], a1[4];
        #pragma unroll
        for (int j = 0; j < 4; ++j) { wud[j] = Wfu[H * H + hb + j]; a0[j] = 0.f; a1[j] = 0.f; }
        const float* r0 = ds + n0 * SDS;
        const float* r1 = ds + n1 * SDS;
        for (int e8 = 0; e8 < TEB; e8 += 8) {
            const float4 d0a = *(const float4*)(r0 + e8);
            const float4 d0b = *(const float4*)(r0 + e8 + 4);
            const float4 d1a = *(const float4*)(r1 + e8);
            const float4 d1b = *(const float4*)(r1 + e8 + 4);
            #pragma unroll
            for (int j = 0; j < 4; ++j) {
                const float* wr = bufAT + (hb + j) * SBT + e8;
                const float4 wA = *(const float4*)(wr);
                const float4 wB = *(const float4*)(wr + 4);
                a0[j] += relu_dot4(d0a, wud[j], wA) + relu_dot4(d0b, wud[j], wB);
                a1[j] += relu_dot4(d1a, wud[j], wA) + relu_dot4(d1b, wud[j], wB);
            }
        }
        if (ATOMIC) {
            float* p0 = outp + n0 * H + hb;
            float* p1 = outp + n1 * H + hb;
            #pragma unroll
            for (int j = 0; j < 4; ++j) { atomicAdd(&p0[j], a0[j]); atomicAdd(&p1[j], a1[j]); }
        } else {
            float* base = outp + (long)blockIdx.x * PSZ;
            *(float4*)(base + n0 * H + hb) = make_float4(a0[0], a0[1], a0[2], a0[3]);
            *(float4*)(base + n1 * H + hb) = make_float4(a1[0], a1[1], a1[2], a1[3]);
        }
    }
}

// =====================================================================
// kCf17: fused v-chain + z partials. u_l in LDS (pre-scaled); query
// rows read from global in ph4 (as r8).
// =====================================================================
template<bool ATOMIC>
__global__ __launch_bounds__(512, 4) void kCf17(
    const float* __restrict__ d, const float* __restrict__ d2,
    const float* __restrict__ uwb,
    const float* __restrict__ Wfvc,
    const float* __restrict__ Wgvc, const float* __restrict__ bgvc,
    const float* __restrict__ Wfz,  const float* __restrict__ bfz,
    float* __restrict__ outp)
{
    __shared__ __align__(16) float ds[N1 * SDS];
    __shared__ __align__(16) float bufAT[4352];
    __shared__ __align__(16) float bufB[4352];
    float* u_l = bufB;   // [60][32] overlay: read in ph1, dead before ph2 writes
    const int tid = threadIdx.x;
    const long sE = (long)blockIdx.x * TEB;

    // ph0: stage support tile + uwb (pre-scaled by 1/N1)
    for (int i = tid; i < N1 * (TEB / 4); i += 512) {
        const int n = i >> 5, c = (i & 31) * 4;
        *(float4*)(ds + n * SDS + c) = *(const float4*)(d + (long)n * E_DIM + sE + c);
    }
    if (tid < PSZ / 4) {
        float4 u = ((const float4*)uwb)[tid];
        u.x *= (1.f / N1); u.y *= (1.f / N1); u.z *= (1.f / N1); u.w *= (1.f / N1);
        ((float4*)u_l)[tid] = u;
    }
    __syncthreads();

    const int eL = tid & 63;
    const int h0 = __builtin_amdgcn_readfirstlane((tid >> 6) * 4);

    // ph1: m = mean_n relu(d*wvd + u); two e's, dual-n
    {
        float wvd[4], mA0[4], mA1[4], mB0[4], mB1[4];
        #pragma unroll
        for (int j = 0; j < 4; ++j) {
            wvd[j] = Wfvc[H * H + h0 + j] * (1.f / N1);
            mA0[j] = 0.f; mA1[j] = 0.f; mB0[j] = 0.f; mB1[j] = 0.f;
        }
        const float* dp0 = ds + eL;
        const float* dp1 = ds + eL + 64;
        #pragma unroll 5
        for (int n = 0; n < N1; n += 2) {
            const float a0 = dp0[n * SDS],       a1 = dp1[n * SDS];
            const float b0 = dp0[(n + 1) * SDS], b1 = dp1[(n + 1) * SDS];
            const float4 u0 = *(const float4*)(u_l + n * H + h0);        // broadcast
            const float4 u1 = *(const float4*)(u_l + (n + 1) * H + h0);  // broadcast
            const float ua[4] = {u0.x, u0.y, u0.z, u0.w};
            const float ub[4] = {u1.x, u1.y, u1.z, u1.w};
            #pragma unroll
            for (int j = 0; j < 4; ++j) {
                mA0[j] += fmaxf(fmaf(a0, wvd[j], ua[j]), 0.f);
                mA1[j] += fmaxf(fmaf(a1, wvd[j], ua[j]), 0.f);
                mB0[j] += fmaxf(fmaf(b0, wvd[j], ub[j]), 0.f);
                mB1[j] += fmaxf(fmaf(b1, wvd[j], ub[j]), 0.f);
            }
        }
        #pragma unroll
        for (int j = 0; j < 4; ++j) {
            bufAT[eL * SBA + h0 + j]        = mA0[j] + mB0[j];
            bufAT[(eL + 64) * SBA + h0 + j] = mA1[j] + mB1[j];
        }
    }
    __syncthreads();

    // ph2: v = relu(m @ Wgvc + bgvc) -> bufB (u_l dead)
    {
        float a0[4], a1[4];
        #pragma unroll
        for (int j = 0; j < 4; ++j) { a0[j] = bgvc[h0 + j]; a1[j] = a0[j]; }
        #pragma unroll
        for (int k = 0; k < H; ++k) {
            const float t0 = bufAT[eL * SBA + k];
            const float t1 = bufAT[(eL + 64) * SBA + k];
            #pragma unroll
            for (int j = 0; j < 4; ++j) {
                const float w = Wgvc[k * H + h0 + j];
                a0[j] = fmaf(t0, w, a0[j]);
                a1[j] = fmaf(t1, w, a1[j]);
            }
        }
        #pragma unroll
        for (int j = 0; j < 4; ++j) {
            bufB[eL * SBA + h0 + j]        = fmaxf(a0[j], 0.f);
            bufB[(eL + 64) * SBA + h0 + j] = fmaxf(a1[j], 0.f);
        }
    }
    __syncthreads();

    // ph3: vz = v @ Wz_v + b_fz -> bufT
    {
        float a0[4], a1[4];
        #pragma unroll
        for (int j = 0; j < 4; ++j) { a0[j] = bfz[h0 + j]; a1[j] = a0[j]; }
        #pragma unroll
        for (int k = 0; k < H; ++k) {
            const float t0 = bufB[eL * SBA + k];
            const float t1 = bufB[(eL + 64) * SBA + k];
            #pragma unroll
            for (int j = 0; j < 4; ++j) {
                const float w = Wfz[k * H + h0 + j];
                a0[j] = fmaf(t0, w, a0[j]);
                a1[j] = fmaf(t1, w, a1[j]);
            }
        }
        #pragma unroll
        for (int j = 0; j < 4; ++j) {
            bufAT[(h0 + j) * SBT + eL]      = a0[j];
            bufAT[(h0 + j) * SBT + eL + 64] = a1[j];
        }
    }
    __syncthreads();

    // ph4: z partials over query rows (global first-touch), vz from LDS
    if (tid < (N1 / 2) * 8) {
        const int np = tid >> 3, hb = (tid & 7) * 4;
        const int n0 = 2 * np, n1 = n0 + 1;
        float wzd[4], a0[4], a1[4];
        #pragma unroll
        for (int j = 0; j < 4; ++j) { wzd[j] = Wfz[H * H + hb + j]; a0[j] = 0.f; a1[j] = 0.f; }
        const float* r0 = d2 + (long)n0 * E_DIM + sE;
        const float* r1 = d2 + (long)n1 * E_DIM + sE;
        for (int e8 = 0; e8 < TEB; e8 += 8) {
            const float4 d0a = *(const float4*)(r0 + e8);
            const float4 d0b = *(const float4*)(r0 + e8 + 4);
            const float4 d1a = *(const float4*)(r1 + e8);
            const float4 d1b = *(const float4*)(r1 + e8 + 4);
            #pragma unroll
            for (int j = 0; j < 4; ++j) {
                const float* wr = bufAT + (hb + j) * SBT + e8;
                const float4 wA = *(const float4*)(wr);
                const float4 wB = *(const float4*)(wr + 4);
                a0[j] += relu_dot4(d0a, wzd[j], wA) + relu_dot4(d0b, wzd[j], wB);
                a1[j] += relu_dot4(d1a, wzd[j], wA) + relu_dot4(d1b, wzd[j], wB);
            }
        }
        if (ATOMIC) {
            float* p0 = outp + n0 * H + hb;
            float* p1 = outp + n1 * H + hb;
            #pragma unroll
            for (int j = 0; j < 4; ++j) { atomicAdd(&p0[j], a0[j]); atomicAdd(&p1[j], a1[j]); }
        } else {
            float* base = outp + (long)blockIdx.x * PSZ;
            *(float4*)(base + n0 * H + hb) = make_float4(a0[0], a0[1], a0[2], a0[3]);
            *(float4*)(base + n1 * H + hb) = make_float4(a1[0], a1[1], a1[2], a1[3]);
        }
    }
}

// reduce part[NB2][PSZ] -> out[PSZ]; grid = PSZ/16 = 120 blocks
__global__ __launch_bounds__(256) void kR(
    const float* __restrict__ part, float* __restrict__ out)
{
    __shared__ float red[16][17];
    const int tid = threadIdx.x;
    const int oLoc = tid & 15, c = tid >> 4;
    const int o = blockIdx.x * 16 + oLoc;
    const int b0 = c * 34;
    const int bN = (NB2 - b0 < 34) ? (NB2 - b0) : 34;
    const float* p = part + (long)b0 * PSZ + o;
    float s = 0.f;
    #pragma unroll 2
    for (int b = 0; b < bN; ++b) s += p[(long)b * PSZ];
    red[c][oLoc] = s;
    __syncthreads();
    if (tid < 16) {
        float t = 0.f;
        #pragma unroll
        for (int ci = 0; ci < 16; ++ci) t += red[ci][tid];
        out[blockIdx.x * 16 + tid] = t;
    }
}

__global__ __launch_bounds__(1024) void kB(
    const float* __restrict__ alphaAcc, const int* __restrict__ label,
    const float* __restrict__ Wfvb, const float* __restrict__ bfvb,
    const float* __restrict__ Wgvb, const float* __restrict__ bgvb,
    const float* __restrict__ Wfu,  const float* __restrict__ bfu,
    const float* __restrict__ Wgu,  const float* __restrict__ bgu,
    const float* __restrict__ Wfvc, const float* __restrict__ bfvc,
    float* __restrict__ uwb)
{
    __shared__ float up_l[N1 * H];
    __shared__ float un_l[N1 * H];
    __shared__ float cb_l[CC * H];
    __shared__ float cw_l[CC * H];
    __shared__ int   cnt[CC];
    const int tid = threadIdx.x;

    if (tid < CC) cnt[tid] = 0;
    __syncthreads();
    if (tid < N1) atomicAdd(&cnt[label[tid]], 1);
    __syncthreads();

    if (tid < CC * H) {
        const int c = tid / H, h = tid % H;
        const float nc = (float)cnt[c];
        float s = bgvb[h];
        #pragma unroll
        for (int k = 0; k < H; ++k) {
            const float t1c = (nc * fmaxf(Wfvb[k] + bfvb[k], 0.f) +
                               ((float)N1 - nc) * fmaxf(bfvb[k], 0.f)) * (1.f / N1);
            s = fmaf(t1c, Wgvb[k * H + h], s);
        }
        cb_l[tid] = fmaxf(s, 0.f);
    }
    __syncthreads();
    if (tid < CC * H) {
        const int c = tid / H, h = tid % H;
        float s = bfu[h];
        #pragma unroll
        for (int k = 0; k < H; ++k) s = fmaf(cb_l[c * H + k], Wfu[k * H + h], s);
        cw_l[tid] = s;
    }
    __syncthreads();
    for (int t = tid; t < N1 * H; t += 1024) {
        const int n = t >> 5, h = t & 31;
        const int ln = label[n];
        const float wud = Wfu[H * H + h];
        float s = 0.f;
        #pragma unroll
        for (int c = 0; c < CC; ++c)
            s += fmaxf(cw_l[c * H + h] + ((c == ln) ? wud : 0.f), 0.f);
        up_l[t] = alphaAcc[t] * (1.f / E_DIM) + s * (1.f / CC);
    }
    __syncthreads();
    for (int t = tid; t < N1 * H; t += 1024) {
        const int n = t >> 5, h = t & 31;
        float s = bgu[h];
        #pragma unroll
        for (int k = 0; k < H; ++k) s = fmaf(up_l[n * H + k], Wgu[k * H + h], s);
        un_l[t] = fmaxf(s, 0.f);
    }
    __syncthreads();
    for (int t = tid; t < N1 * H; t += 1024) {
        const int n = t >> 5, h = t & 31;
        float s = bfvc[h];
        #pragma unroll
        for (int k = 0; k < H; ++k) s = fmaf(un_l[n * H + k], Wfvc[k * H + h], s);
        uwb[t] = s;
    }
}

__global__ __launch_bounds__(1024) void kD(
    const float* __restrict__ zAcc,
    const float* __restrict__ Wgz, const float* __restrict__ bgz,
    float* __restrict__ out)
{
    __shared__ float z_l[N1 * H];
    const int tid = threadIdx.x;
    for (int t = tid; t < N1 * H; t += 1024) z_l[t] = zAcc[t] * (1.f / E_DIM);
    __syncthreads();
    for (int t = tid; t < N1 * H; t += 1024) {
        const int n = t >> 5, h = t & 31;
        float s = bgz[h];
        #pragma unroll
        for (int k = 0; k < H; ++k) s = fmaf(z_l[n * H + k], Wgz[k * H + h], s);
        out[t] = fmaxf(s, 0.f);
    }
}

extern "C" void kernel_launch(void* const* d_in, const int* in_sizes, int n_in,
                              void* d_out, int out_size, void* d_ws, size_t ws_size,
                              hipStream_t stream)
{
    const float* sup  = (const float*)d_in[0];
    const int*   lab  = (const int*)d_in[1];
    const float* qry  = (const float*)d_in[2];
    const float* Wfvb = (const float*)d_in[3];
    const float* bfvb = (const float*)d_in[4];
    const float* Wgvb = (const float*)d_in[5];
    const float* bgvb = (const float*)d_in[6];
    const float* Wfu  = (const float*)d_in[7];
    const float* bfu  = (const float*)d_in[8];
    const float* Wgu  = (const float*)d_in[9];
    const float* bgu  = (const float*)d_in[10];
    const float* Wfvc = (const float*)d_in[11];
    const float* bfvc = (const float*)d_in[12];
    const float* Wgvc = (const float*)d_in[13];
    const float* bgvc = (const float*)d_in[14];
    const float* Wfz  = (const float*)d_in[15];
    const float* bfz  = (const float*)d_in[16];
    const float* Wgz  = (const float*)d_in[17];
    const float* bgz  = (const float*)d_in[18];
    float* out = (float*)d_out;

    float* alphaAcc = (float*)d_ws;
    float* zAcc     = alphaAcc + PSZ;
    float* uwb      = zAcc + PSZ;
    float* partA    = uwb + PSZ;
    float* partZ    = partA + (size_t)NB2 * PSZ;

    const size_t needMain = (3 * (size_t)PSZ + 2 * (size_t)NB2 * PSZ) * sizeof(float);

    if (ws_size >= needMain) {
        kA17<false><<<NB2, 512, 0, stream>>>(sup, Wfvb, bfvb, Wgvb, bgvb, Wfu, bfu, partA);
        kR<<<PSZ / 16, 256, 0, stream>>>(partA, alphaAcc);
        kB<<<1, 1024, 0, stream>>>(alphaAcc, lab, Wfvb, bfvb, Wgvb, bgvb, Wfu, bfu,
                                   Wgu, bgu, Wfvc, bfvc, uwb);
        kCf17<false><<<NB2, 512, 0, stream>>>(sup, qry, uwb, Wfvc, Wgvc, bgvc, Wfz, bfz, partZ);
        kR<<<PSZ / 16, 256, 0, stream>>>(partZ, zAcc);
        kD<<<1, 1024, 0, stream>>>(zAcc, Wgz, bgz, out);
    } else {
        (void)hipMemsetAsync(alphaAcc, 0, 2 * PSZ * sizeof(float), stream);
        kA17<true><<<NB2, 512, 0, stream>>>(sup, Wfvb, bfvb, Wgvb, bgvb, Wfu, bfu, alphaAcc);
        kB<<<1, 1024, 0, stream>>>(alphaAcc, lab, Wfvb, bfvb, Wgvb, bgvb, Wfu, bfu,
                                   Wgu, bgu, Wfvc, bfvc, uwb);
        kCf17<true><<<NB2, 512, 0, stream>>>(sup, qry, uwb, Wfvc, Wgvc, bgvc, Wfz, bfz, zAcc);
        kD<<<1, 1024, 0, stream>>>(zAcc, Wgz, bgz, out);
    }
}

// Round 13
// 94.348 us; speedup vs baseline: 2.7432x; 1.1328x over previous
//
#include <hip/hip_runtime.h>

#define E_DIM 69120
#define N1 60
#define H 32
#define CC 3
#define TEB 64
#define NB2 (E_DIM / TEB)   // 1080
#define SDS 68              // d-tile stride (floats); rows 16B-aligned
#define SBA 34              // chain buffer stride
#define SBT 68              // bufT stride (16B-aligned rows for b128)
#define PSZ (N1 * H)        // 1920

__device__ __forceinline__ float relu_dot4(const float4 d, const float w, const float4 t) {
    return fmaxf(fmaf(d.x, w, t.x), 0.f) + fmaxf(fmaf(d.y, w, t.y), 0.f)
         + fmaxf(fmaf(d.z, w, t.z), 0.f) + fmaxf(fmaf(d.w, w, t.w), 0.f);
}

// LDS: ds[60*68]=4080f | bufA[64*34]=2176f (bufT[32][68] overlay)
//      | bufB[64*34]=2176f (u_l overlay in kCf) -> 33,728 B -> 4 blocks/CU

// =====================================================================
// kA19: v_bar chain + alpha partials.
// ph1-3: (eL 0..63, hg 0..7 -> 4h).  ph4: wave r owns n in [8r, 8r+8),
// lane = (nq2 0..1 -> 4n, hl 0..31 -> 1h): VALU-bound, broadcast reads.
// =====================================================================
template<bool ATOMIC>
__global__ __launch_bounds__(512, 4) void kA19(
    const float* __restrict__ d,
    const float* __restrict__ Wfvb, const float* __restrict__ bfvb,
    const float* __restrict__ Wgvb, const float* __restrict__ bgvb,
    const float* __restrict__ Wfu,  const float* __restrict__ bfu,
    float* __restrict__ outp)
{
    __shared__ __align__(16) float ds[N1 * SDS];
    __shared__ __align__(16) float bufA[64 * SBA];
    __shared__ __align__(16) float bufB[64 * SBA];
    float* bufT = bufA;   // [32][SBT] overlay after bufA dead
    const int tid = threadIdx.x;
    const long sE = (long)blockIdx.x * TEB;

    // ph0: stage support tile
    for (int i = tid; i < N1 * (TEB / 4); i += 512) {
        const int n = i >> 4, c = (i & 15) * 4;
        *(float4*)(ds + n * SDS + c) = *(const float4*)(d + (long)n * E_DIM + sE + c);
    }
    __syncthreads();

    const int eL = tid & 63;
    const int h0 = __builtin_amdgcn_readfirstlane((tid >> 6) * 4);

    // ph1: t1 = mean_n relu(d*wf + bf); dual-n acc; 1/N1 folded
    {
        float wf[4], bf[4], ta[4], tb[4];
        #pragma unroll
        for (int j = 0; j < 4; ++j) {
            wf[j] = Wfvb[h0 + j] * (1.f / N1);
            bf[j] = bfvb[h0 + j] * (1.f / N1);
            ta[j] = 0.f; tb[j] = 0.f;
        }
        const float* dp = ds + eL;
        #pragma unroll 5
        for (int n = 0; n < N1; n += 2) {
            const float dv0 = dp[n * SDS];
            const float dv1 = dp[(n + 1) * SDS];
            #pragma unroll
            for (int j = 0; j < 4; ++j) {
                ta[j] += fmaxf(fmaf(dv0, wf[j], bf[j]), 0.f);
                tb[j] += fmaxf(fmaf(dv1, wf[j], bf[j]), 0.f);
            }
        }
        #pragma unroll
        for (int j = 0; j < 4; ++j) bufA[eL * SBA + h0 + j] = ta[j] + tb[j];
    }
    __syncthreads();

    // ph2: vb = relu(t1 @ Wgvb + bgvb) -> bufB
    {
        float acc[4];
        #pragma unroll
        for (int j = 0; j < 4; ++j) acc[j] = bgvb[h0 + j];
        #pragma unroll
        for (int k = 0; k < H; ++k) {
            const float t = bufA[eL * SBA + k];
            #pragma unroll
            for (int j = 0; j < 4; ++j) acc[j] = fmaf(t, Wgvb[k * H + h0 + j], acc[j]);
        }
        #pragma unroll
        for (int j = 0; j < 4; ++j) bufB[eL * SBA + h0 + j] = fmaxf(acc[j], 0.f);
    }
    __syncthreads();

    // ph3: vw = vb @ Wu_v + b_fu -> bufT (transposed; bufA dead)
    {
        float acc[4];
        #pragma unroll
        for (int j = 0; j < 4; ++j) acc[j] = bfu[h0 + j];
        #pragma unroll
        for (int k = 0; k < H; ++k) {
            const float t = bufB[eL * SBA + k];
            #pragma unroll
            for (int j = 0; j < 4; ++j) acc[j] = fmaf(t, Wfu[k * H + h0 + j], acc[j]);
        }
        #pragma unroll
        for (int j = 0; j < 4; ++j) bufT[(h0 + j) * SBT + eL] = acc[j];
    }
    __syncthreads();

    // ph4: alpha partials. wave r: n in [8r,8r+8); lane: nq2 (4 n's), hl (1 h).
    {
        const int hl = tid & 31;
        const int bn = ((tid >> 6) << 3) + ((tid >> 5) & 1) * 4;
        if (bn < N1) {
            const float wv = Wfu[H * H + hl];
            float acc[4] = {0.f, 0.f, 0.f, 0.f};
            const float* dr = ds + bn * SDS;
            #pragma unroll 2
            for (int e4 = 0; e4 < TEB; e4 += 4) {
                const float4 w4 = *(const float4*)(bufT + hl * SBT + e4);
                #pragma unroll
                for (int i = 0; i < 4; ++i) {
                    const float4 di = *(const float4*)(dr + i * SDS + e4);
                    acc[i] += relu_dot4(di, wv, w4);
                }
            }
            if (ATOMIC) {
                #pragma unroll
                for (int i = 0; i < 4; ++i) atomicAdd(&outp[(bn + i) * H + hl], acc[i]);
            } else {
                float* base = outp + (long)blockIdx.x * PSZ;
                #pragma unroll
                for (int i = 0; i < 4; ++i) base[(bn + i) * H + hl] = acc[i];
            }
        }
    }
}

// =====================================================================
// kCf19: fused v-chain + z partials. Query read from global in ph4.
// =====================================================================
template<bool ATOMIC>
__global__ __launch_bounds__(512, 4) void kCf19(
    const float* __restrict__ d, const float* __restrict__ d2,
    const float* __restrict__ uwb,
    const float* __restrict__ Wfvc,
    const float* __restrict__ Wgvc, const float* __restrict__ bgvc,
    const float* __restrict__ Wfz,  const float* __restrict__ bfz,
    float* __restrict__ outp)
{
    __shared__ __align__(16) float ds[N1 * SDS];
    __shared__ __align__(16) float bufA[64 * SBA];
    __shared__ __align__(16) float bufB[64 * SBA];
    float* bufT = bufA;
    float* u_l  = bufB;   // [60][32] overlay: read in ph1, dead before ph2 writes
    const int tid = threadIdx.x;
    const long sE = (long)blockIdx.x * TEB;

    // ph0: stage support tile + uwb (pre-scaled by 1/N1)
    for (int i = tid; i < N1 * (TEB / 4); i += 512) {
        const int n = i >> 4, c = (i & 15) * 4;
        *(float4*)(ds + n * SDS + c) = *(const float4*)(d + (long)n * E_DIM + sE + c);
    }
    if (tid < PSZ / 4) {
        float4 u = ((const float4*)uwb)[tid];
        u.x *= (1.f / N1); u.y *= (1.f / N1); u.z *= (1.f / N1); u.w *= (1.f / N1);
        ((float4*)u_l)[tid] = u;
    }
    __syncthreads();

    const int eL = tid & 63;
    const int h0 = __builtin_amdgcn_readfirstlane((tid >> 6) * 4);

    // ph1: m = mean_n relu(d*wvd + u); dual-n
    {
        float wvd[4], ma[4], mb[4];
        #pragma unroll
        for (int j = 0; j < 4; ++j) { wvd[j] = Wfvc[H * H + h0 + j] * (1.f / N1); ma[j] = 0.f; mb[j] = 0.f; }
        const float* dp = ds + eL;
        #pragma unroll 5
        for (int n = 0; n < N1; n += 2) {
            const float dv0 = dp[n * SDS];
            const float dv1 = dp[(n + 1) * SDS];
            const float4 u0 = *(const float4*)(u_l + n * H + h0);        // broadcast
            const float4 u1 = *(const float4*)(u_l + (n + 1) * H + h0);  // broadcast
            ma[0] += fmaxf(fmaf(dv0, wvd[0], u0.x), 0.f);
            ma[1] += fmaxf(fmaf(dv0, wvd[1], u0.y), 0.f);
            ma[2] += fmaxf(fmaf(dv0, wvd[2], u0.z), 0.f);
            ma[3] += fmaxf(fmaf(dv0, wvd[3], u0.w), 0.f);
            mb[0] += fmaxf(fmaf(dv1, wvd[0], u1.x), 0.f);
            mb[1] += fmaxf(fmaf(dv1, wvd[1], u1.y), 0.f);
            mb[2] += fmaxf(fmaf(dv1, wvd[2], u1.z), 0.f);
            mb[3] += fmaxf(fmaf(dv1, wvd[3], u1.w), 0.f);
        }
        #pragma unroll
        for (int j = 0; j < 4; ++j) bufA[eL * SBA + h0 + j] = ma[j] + mb[j];
    }
    __syncthreads();

    // ph2: v = relu(m @ Wgvc + bgvc) -> bufB (u_l dead)
    {
        float acc[4];
        #pragma unroll
        for (int j = 0; j < 4; ++j) acc[j] = bgvc[h0 + j];
        #pragma unroll
        for (int k = 0; k < H; ++k) {
            const float t = bufA[eL * SBA + k];
            #pragma unroll
            for (int j = 0; j < 4; ++j) acc[j] = fmaf(t, Wgvc[k * H + h0 + j], acc[j]);
        }
        #pragma unroll
        for (int j = 0; j < 4; ++j) bufB[eL * SBA + h0 + j] = fmaxf(acc[j], 0.f);
    }
    __syncthreads();

    // ph3: vz = v @ Wz_v + b_fz -> bufT (bufA dead)
    {
        float acc[4];
        #pragma unroll
        for (int j = 0; j < 4; ++j) acc[j] = bfz[h0 + j];
        #pragma unroll
        for (int k = 0; k < H; ++k) {
            const float t = bufB[eL * SBA + k];
            #pragma unroll
            for (int j = 0; j < 4; ++j) acc[j] = fmaf(t, Wfz[k * H + h0 + j], acc[j]);
        }
        #pragma unroll
        for (int j = 0; j < 4; ++j) bufT[(h0 + j) * SBT + eL] = acc[j];
    }
    __syncthreads();

    // ph4: z partials. wave r: n in [8r,8r+8); query rows from GLOBAL.
    {
        const int hl = tid & 31;
        const int bn = ((tid >> 6) << 3) + ((tid >> 5) & 1) * 4;
        if (bn < N1) {
            const float wv = Wfz[H * H + hl];
            float acc[4] = {0.f, 0.f, 0.f, 0.f};
            const float* dr = d2 + (long)bn * E_DIM + sE;
            #pragma unroll 2
            for (int e4 = 0; e4 < TEB; e4 += 4) {
                const float4 w4 = *(const float4*)(bufT + hl * SBT + e4);
                #pragma unroll
                for (int i = 0; i < 4; ++i) {
                    const float4 di = *(const float4*)(dr + (long)i * E_DIM + e4);
                    acc[i] += relu_dot4(di, wv, w4);
                }
            }
            if (ATOMIC) {
                #pragma unroll
                for (int i = 0; i < 4; ++i) atomicAdd(&outp[(bn + i) * H + hl], acc[i]);
            } else {
                float* base = outp + (long)blockIdx.x * PSZ;
                #pragma unroll
                for (int i = 0; i < 4; ++i) base[(bn + i) * H + hl] = acc[i];
            }
        }
    }
}

// reduce part[NB2][PSZ] -> out[PSZ]; grid = PSZ/16 = 120 blocks
__global__ __launch_bounds__(256) void kR(
    const float* __restrict__ part, float* __restrict__ out)
{
    __shared__ float red[16][17];
    const int tid = threadIdx.x;
    const int oLoc = tid & 15, c = tid >> 4;
    const int o = blockIdx.x * 16 + oLoc;
    const int b0 = c * 68;
    const int bN = (NB2 - b0 < 68) ? (NB2 - b0) : 68;
    const float* p = part + (long)b0 * PSZ + o;
    float s = 0.f;
    #pragma unroll 4
    for (int b = 0; b < bN; ++b) s += p[(long)b * PSZ];
    red[c][oLoc] = s;
    __syncthreads();
    if (tid < 16) {
        float t = 0.f;
        #pragma unroll
        for (int ci = 0; ci < 16; ++ci) t += red[ci][tid];
        out[blockIdx.x * 16 + tid] = t;
    }
}

__global__ __launch_bounds__(1024) void kB(
    const float* __restrict__ alphaAcc, const int* __restrict__ label,
    const float* __restrict__ Wfvb, const float* __restrict__ bfvb,
    const float* __restrict__ Wgvb, const float* __restrict__ bgvb,
    const float* __restrict__ Wfu,  const float* __restrict__ bfu,
    const float* __restrict__ Wgu,  const float* __restrict__ bgu,
    const float* __restrict__ Wfvc, const float* __restrict__ bfvc,
    float* __restrict__ uwb)
{
    __shared__ float up_l[N1 * H];
    __shared__ float un_l[N1 * H];
    __shared__ float cb_l[CC * H];
    __shared__ float cw_l[CC * H];
    __shared__ int   cnt[CC];
    const int tid = threadIdx.x;

    if (tid < CC) cnt[tid] = 0;
    __syncthreads();
    if (tid < N1) atomicAdd(&cnt[label[tid]], 1);
    __syncthreads();

    if (tid < CC * H) {
        const int c = tid / H, h = tid % H;
        const float nc = (float)cnt[c];
        float s = bgvb[h];
        #pragma unroll
        for (int k = 0; k < H; ++k) {
            const float t1c = (nc * fmaxf(Wfvb[k] + bfvb[k], 0.f) +
                               ((float)N1 - nc) * fmaxf(bfvb[k], 0.f)) * (1.f / N1);
            s = fmaf(t1c, Wgvb[k * H + h], s);
        }
        cb_l[tid] = fmaxf(s, 0.f);
    }
    __syncthreads();
    if (tid < CC * H) {
        const int c = tid / H, h = tid % H;
        float s = bfu[h];
        #pragma unroll
        for (int k = 0; k < H; ++k) s = fmaf(cb_l[c * H + k], Wfu[k * H + h], s);
        cw_l[tid] = s;
    }
    __syncthreads();
    for (int t = tid; t < N1 * H; t += 1024) {
        const int n = t >> 5, h = t & 31;
        const int ln = label[n];
        const float wud = Wfu[H * H + h];
        float s = 0.f;
        #pragma unroll
        for (int c = 0; c < CC; ++c)
            s += fmaxf(cw_l[c * H + h] + ((c == ln) ? wud : 0.f), 0.f);
        up_l[t] = alphaAcc[t] * (1.f / E_DIM) + s * (1.f / CC);
    }
    __syncthreads();
    for (int t = tid; t < N1 * H; t += 1024) {
        const int n = t >> 5, h = t & 31;
        float s = bgu[h];
        #pragma unroll
        for (int k = 0; k < H; ++k) s = fmaf(up_l[n * H + k], Wgu[k * H + h], s);
        un_l[t] = fmaxf(s, 0.f);
    }
    __syncthreads();
    for (int t = tid; t < N1 * H; t += 1024) {
        const int n = t >> 5, h = t & 31;
        float s = bfvc[h];
        #pragma unroll
        for (int k = 0; k < H; ++k) s = fmaf(un_l[n * H + k], Wfvc[k * H + h], s);
        uwb[t] = s;
    }
}

__global__ __launch_bounds__(1024) void kD(
    const float* __restrict__ zAcc,
    const float* __restrict__ Wgz, const float* __restrict__ bgz,
    float* __restrict__ out)
{
    __shared__ float z_l[N1 * H];
    const int tid = threadIdx.x;
    for (int t = tid; t < N1 * H; t += 1024) z_l[t] = zAcc[t] * (1.f / E_DIM);
    __syncthreads();
    for (int t = tid; t < N1 * H; t += 1024) {
        const int n = t >> 5, h = t & 31;
        float s = bgz[h];
        #pragma unroll
        for (int k = 0; k < H; ++k) s = fmaf(z_l[n * H + k], Wgz[k * H + h], s);
        out[t] = fmaxf(s, 0.f);
    }
}

extern "C" void kernel_launch(void* const* d_in, const int* in_sizes, int n_in,
                              void* d_out, int out_size, void* d_ws, size_t ws_size,
                              hipStream_t stream)
{
    const float* sup  = (const float*)d_in[0];
    const int*   lab  = (const int*)d_in[1];
    const float* qry  = (const float*)d_in[2];
    const float* Wfvb = (const float*)d_in[3];
    const float* bfvb = (const float*)d_in[4];
    const float* Wgvb = (const float*)d_in[5];
    const float* bgvb = (const float*)d_in[6];
    const float* Wfu  = (const float*)d_in[7];
    const float* bfu  = (const float*)d_in[8];
    const float* Wgu  = (const float*)d_in[9];
    const float* bgu  = (const float*)d_in[10];
    const float* Wfvc = (const float*)d_in[11];
    const float* bfvc = (const float*)d_in[12];
    const float* Wgvc = (const float*)d_in[13];
    const float* bgvc = (const float*)d_in[14];
    const float* Wfz  = (const float*)d_in[15];
    const float* bfz  = (const float*)d_in[16];
    const float* Wgz  = (const float*)d_in[17];
    const float* bgz  = (const float*)d_in[18];
    float* out = (float*)d_out;

    float* alphaAcc = (float*)d_ws;
    float* zAcc     = alphaAcc + PSZ;
    float* uwb      = zAcc + PSZ;
    float* partA    = uwb + PSZ;
    float* partZ    = partA + (size_t)NB2 * PSZ;

    const size_t needMain = (3 * (size_t)PSZ + 2 * (size_t)NB2 * PSZ) * sizeof(float);

    if (ws_size >= needMain) {
        kA19<false><<<NB2, 512, 0, stream>>>(sup, Wfvb, bfvb, Wgvb, bgvb, Wfu, bfu, partA);
        kR<<<PSZ / 16, 256, 0, stream>>>(partA, alphaAcc);
        kB<<<1, 1024, 0, stream>>>(alphaAcc, lab, Wfvb, bfvb, Wgvb, bgvb, Wfu, bfu,
                                   Wgu, bgu, Wfvc, bfvc, uwb);
        kCf19<false><<<NB2, 512, 0, stream>>>(sup, qry, uwb, Wfvc, Wgvc, bgvc, Wfz, bfz, partZ);
        kR<<<PSZ / 16, 256, 0, stream>>>(partZ, zAcc);
        kD<<<1, 1024, 0, stream>>>(zAcc, Wgz, bgz, out);
    } else {
        (void)hipMemsetAsync(alphaAcc, 0, 2 * PSZ * sizeof(float), stream);
        kA19<true><<<NB2, 512, 0, stream>>>(sup, Wfvb, bfvb, Wgvb, bgvb, Wfu, bfu, alphaAcc);
        kB<<<1, 1024, 0, stream>>>(alphaAcc, lab, Wfvb, bfvb, Wgvb, bgvb, Wfu, bfu,
                                   Wgu, bgu, Wfvc, bfvc, uwb);
        kCf19<true><<<NB2, 512, 0, stream>>>(sup, qry, uwb, Wfvc, Wgvc, bgvc, Wfz, bfz, zAcc);
        kD<<<1, 1024, 0, stream>>>(zAcc, Wgz, bgz, out);
    }
}

// Round 14
// 89.902 us; speedup vs baseline: 2.8789x; 1.0495x over previous
//
#include <hip/hip_runtime.h>

#define E_DIM 69120
#define N1 60
#define H 32
#define CC 3
#define TEB 64
#define NB2 (E_DIM / TEB)   // 1080
#define SDS 68              // d-tile stride (floats); rows 16B-aligned
#define SBA 34              // chain buffer stride
#define SBT 68              // bufT stride (16B-aligned rows for b128)
#define PSZ (N1 * H)        // 1920

__device__ __forceinline__ float relu_dot4(const float4 d, const float w, const float4 t) {
    return fmaxf(fmaf(d.x, w, t.x), 0.f) + fmaxf(fmaf(d.y, w, t.y), 0.f)
         + fmaxf(fmaf(d.z, w, t.z), 0.f) + fmaxf(fmaf(d.w, w, t.w), 0.f);
}

// LDS: ds[60*68]=4080f | bufA[64*34]=2176f (bufT[32][68] overlay)
//      | bufB[64*34]=2176f (u_l overlay in kCf) -> 33,728 B -> 4 blocks/CU

// =====================================================================
// kA19: v_bar chain + alpha partials.
// ph1-3: (eL 0..63, hg 0..7 -> 4h).  ph4: wave r owns n in [8r, 8r+8),
// lane = (nq2 0..1 -> 4n, hl 0..31 -> 1h): VALU-bound, broadcast reads.
// =====================================================================
template<bool ATOMIC>
__global__ __launch_bounds__(512, 4) void kA19(
    const float* __restrict__ d,
    const float* __restrict__ Wfvb, const float* __restrict__ bfvb,
    const float* __restrict__ Wgvb, const float* __restrict__ bgvb,
    const float* __restrict__ Wfu,  const float* __restrict__ bfu,
    float* __restrict__ outp)
{
    __shared__ __align__(16) float ds[N1 * SDS];
    __shared__ __align__(16) float bufA[64 * SBA];
    __shared__ __align__(16) float bufB[64 * SBA];
    float* bufT = bufA;   // [32][SBT] overlay after bufA dead
    const int tid = threadIdx.x;
    const long sE = (long)blockIdx.x * TEB;

    // ph0: stage support tile
    for (int i = tid; i < N1 * (TEB / 4); i += 512) {
        const int n = i >> 4, c = (i & 15) * 4;
        *(float4*)(ds + n * SDS + c) = *(const float4*)(d + (long)n * E_DIM + sE + c);
    }
    __syncthreads();

    const int eL = tid & 63;
    const int h0 = __builtin_amdgcn_readfirstlane((tid >> 6) * 4);

    // ph1: t1 = mean_n relu(d*wf + bf); dual-n acc; 1/N1 folded
    {
        float wf[4], bf[4], ta[4], tb[4];
        #pragma unroll
        for (int j = 0; j < 4; ++j) {
            wf[j] = Wfvb[h0 + j] * (1.f / N1);
            bf[j] = bfvb[h0 + j] * (1.f / N1);
            ta[j] = 0.f; tb[j] = 0.f;
        }
        const float* dp = ds + eL;
        #pragma unroll 5
        for (int n = 0; n < N1; n += 2) {
            const float dv0 = dp[n * SDS];
            const float dv1 = dp[(n + 1) * SDS];
            #pragma unroll
            for (int j = 0; j < 4; ++j) {
                ta[j] += fmaxf(fmaf(dv0, wf[j], bf[j]), 0.f);
                tb[j] += fmaxf(fmaf(dv1, wf[j], bf[j]), 0.f);
            }
        }
        #pragma unroll
        for (int j = 0; j < 4; ++j) bufA[eL * SBA + h0 + j] = ta[j] + tb[j];
    }
    __syncthreads();

    // ph2: vb = relu(t1 @ Wgvb + bgvb) -> bufB
    {
        float acc[4];
        #pragma unroll
        for (int j = 0; j < 4; ++j) acc[j] = bgvb[h0 + j];
        #pragma unroll
        for (int k = 0; k < H; ++k) {
            const float t = bufA[eL * SBA + k];
            #pragma unroll
            for (int j = 0; j < 4; ++j) acc[j] = fmaf(t, Wgvb[k * H + h0 + j], acc[j]);
        }
        #pragma unroll
        for (int j = 0; j < 4; ++j) bufB[eL * SBA + h0 + j] = fmaxf(acc[j], 0.f);
    }
    __syncthreads();

    // ph3: vw = vb @ Wu_v + b_fu -> bufT (transposed; bufA dead)
    {
        float acc[4];
        #pragma unroll
        for (int j = 0; j < 4; ++j) acc[j] = bfu[h0 + j];
        #pragma unroll
        for (int k = 0; k < H; ++k) {
            const float t = bufB[eL * SBA + k];
            #pragma unroll
            for (int j = 0; j < 4; ++j) acc[j] = fmaf(t, Wfu[k * H + h0 + j], acc[j]);
        }
        #pragma unroll
        for (int j = 0; j < 4; ++j) bufT[(h0 + j) * SBT + eL] = acc[j];
    }
    __syncthreads();

    // ph4: alpha partials. wave r: n in [8r,8r+8); lane: nq2 (4 n's), hl (1 h).
    {
        const int hl = tid & 31;
        const int bn = ((tid >> 6) << 3) + ((tid >> 5) & 1) * 4;
        if (bn < N1) {
            const float wv = Wfu[H * H + hl];
            float acc[4] = {0.f, 0.f, 0.f, 0.f};
            const float* dr = ds + bn * SDS;
            #pragma unroll 2
            for (int e4 = 0; e4 < TEB; e4 += 4) {
                const float4 w4 = *(const float4*)(bufT + hl * SBT + e4);
                #pragma unroll
                for (int i = 0; i < 4; ++i) {
                    const float4 di = *(const float4*)(dr + i * SDS + e4);
                    acc[i] += relu_dot4(di, wv, w4);
                }
            }
            if (ATOMIC) {
                #pragma unroll
                for (int i = 0; i < 4; ++i) atomicAdd(&outp[(bn + i) * H + hl], acc[i]);
            } else {
                float* base = outp + (long)blockIdx.x * PSZ;
                #pragma unroll
                for (int i = 0; i < 4; ++i) base[(bn + i) * H + hl] = acc[i];
            }
        }
    }
}

// =====================================================================
// kCf21: fused v-chain + z partials. Query tile staged into ds (dead
// after ph1); loads issued after B1, hidden under ph2, consumed in ph4.
// =====================================================================
template<bool ATOMIC>
__global__ __launch_bounds__(512, 4) void kCf21(
    const float* __restrict__ d, const float* __restrict__ d2,
    const float* __restrict__ uwb,
    const float* __restrict__ Wfvc,
    const float* __restrict__ Wgvc, const float* __restrict__ bgvc,
    const float* __restrict__ Wfz,  const float* __restrict__ bfz,
    float* __restrict__ outp)
{
    __shared__ __align__(16) float ds[N1 * SDS];
    __shared__ __align__(16) float bufA[64 * SBA];
    __shared__ __align__(16) float bufB[64 * SBA];
    float* bufT = bufA;
    float* u_l  = bufB;   // [60][32] overlay: read in ph1, dead before ph2 writes
    const int tid = threadIdx.x;
    const long sE = (long)blockIdx.x * TEB;

    // ph0: stage support tile + uwb (pre-scaled by 1/N1)
    for (int i = tid; i < N1 * (TEB / 4); i += 512) {
        const int n = i >> 4, c = (i & 15) * 4;
        *(float4*)(ds + n * SDS + c) = *(const float4*)(d + (long)n * E_DIM + sE + c);
    }
    if (tid < PSZ / 4) {
        float4 u = ((const float4*)uwb)[tid];
        u.x *= (1.f / N1); u.y *= (1.f / N1); u.z *= (1.f / N1); u.w *= (1.f / N1);
        ((float4*)u_l)[tid] = u;
    }
    __syncthreads();

    const int eL = tid & 63;
    const int h0 = __builtin_amdgcn_readfirstlane((tid >> 6) * 4);

    // ph1: m = mean_n relu(d*wvd + u); dual-n
    {
        float wvd[4], ma[4], mb[4];
        #pragma unroll
        for (int j = 0; j < 4; ++j) { wvd[j] = Wfvc[H * H + h0 + j] * (1.f / N1); ma[j] = 0.f; mb[j] = 0.f; }
        const float* dp = ds + eL;
        #pragma unroll 5
        for (int n = 0; n < N1; n += 2) {
            const float dv0 = dp[n * SDS];
            const float dv1 = dp[(n + 1) * SDS];
            const float4 u0 = *(const float4*)(u_l + n * H + h0);        // broadcast
            const float4 u1 = *(const float4*)(u_l + (n + 1) * H + h0);  // broadcast
            ma[0] += fmaxf(fmaf(dv0, wvd[0], u0.x), 0.f);
            ma[1] += fmaxf(fmaf(dv0, wvd[1], u0.y), 0.f);
            ma[2] += fmaxf(fmaf(dv0, wvd[2], u0.z), 0.f);
            ma[3] += fmaxf(fmaf(dv0, wvd[3], u0.w), 0.f);
            mb[0] += fmaxf(fmaf(dv1, wvd[0], u1.x), 0.f);
            mb[1] += fmaxf(fmaf(dv1, wvd[1], u1.y), 0.f);
            mb[2] += fmaxf(fmaf(dv1, wvd[2], u1.z), 0.f);
            mb[3] += fmaxf(fmaf(dv1, wvd[3], u1.w), 0.f);
        }
        #pragma unroll
        for (int j = 0; j < 4; ++j) bufA[eL * SBA + h0 + j] = ma[j] + mb[j];
    }
    __syncthreads();   // B1: bufA ready; ds (support) now DEAD

    // issue query-tile loads early; HBM latency hides under ph2
    float4 q0, q1;
    {
        const int n0 = tid >> 4, c0 = (tid & 15) * 4;
        q0 = *(const float4*)(d2 + (long)n0 * E_DIM + sE + c0);
        if (tid < 448) {
            const int i1 = tid + 512, n1 = i1 >> 4, c1 = (i1 & 15) * 4;
            q1 = *(const float4*)(d2 + (long)n1 * E_DIM + sE + c1);
        }
    }

    // ph2: v = relu(m @ Wgvc + bgvc) -> bufB (u_l dead)
    {
        float acc[4];
        #pragma unroll
        for (int j = 0; j < 4; ++j) acc[j] = bgvc[h0 + j];
        #pragma unroll
        for (int k = 0; k < H; ++k) {
            const float t = bufA[eL * SBA + k];
            #pragma unroll
            for (int j = 0; j < 4; ++j) acc[j] = fmaf(t, Wgvc[k * H + h0 + j], acc[j]);
        }
        #pragma unroll
        for (int j = 0; j < 4; ++j) bufB[eL * SBA + h0 + j] = fmaxf(acc[j], 0.f);
    }

    // write query tile into ds (support dead since B1)
    {
        const int n0 = tid >> 4, c0 = (tid & 15) * 4;
        *(float4*)(ds + n0 * SDS + c0) = q0;
        if (tid < 448) {
            const int i1 = tid + 512, n1 = i1 >> 4, c1 = (i1 & 15) * 4;
            *(float4*)(ds + n1 * SDS + c1) = q1;
        }
    }
    __syncthreads();   // B2: bufB + query tile ready

    // ph3: vz = v @ Wz_v + b_fz -> bufT (bufA dead)
    {
        float acc[4];
        #pragma unroll
        for (int j = 0; j < 4; ++j) acc[j] = bfz[h0 + j];
        #pragma unroll
        for (int k = 0; k < H; ++k) {
            const float t = bufB[eL * SBA + k];
            #pragma unroll
            for (int j = 0; j < 4; ++j) acc[j] = fmaf(t, Wfz[k * H + h0 + j], acc[j]);
        }
        #pragma unroll
        for (int j = 0; j < 4; ++j) bufT[(h0 + j) * SBT + eL] = acc[j];
    }
    __syncthreads();   // B3: bufT ready

    // ph4: z partials. wave r: n in [8r,8r+8); query rows from LDS now.
    {
        const int hl = tid & 31;
        const int bn = ((tid >> 6) << 3) + ((tid >> 5) & 1) * 4;
        if (bn < N1) {
            const float wv = Wfz[H * H + hl];
            float acc[4] = {0.f, 0.f, 0.f, 0.f};
            const float* dr = ds + bn * SDS;
            #pragma unroll 2
            for (int e4 = 0; e4 < TEB; e4 += 4) {
                const float4 w4 = *(const float4*)(bufT + hl * SBT + e4);
                #pragma unroll
                for (int i = 0; i < 4; ++i) {
                    const float4 di = *(const float4*)(dr + i * SDS + e4);
                    acc[i] += relu_dot4(di, wv, w4);
                }
            }
            if (ATOMIC) {
                #pragma unroll
                for (int i = 0; i < 4; ++i) atomicAdd(&outp[(bn + i) * H + hl], acc[i]);
            } else {
                float* base = outp + (long)blockIdx.x * PSZ;
                #pragma unroll
                for (int i = 0; i < 4; ++i) base[(bn + i) * H + hl] = acc[i];
            }
        }
    }
}

// reduce part[NB2][PSZ] -> out[PSZ]; grid = PSZ/16 = 120 blocks
__global__ __launch_bounds__(256) void kR(
    const float* __restrict__ part, float* __restrict__ out)
{
    __shared__ float red[16][17];
    const int tid = threadIdx.x;
    const int oLoc = tid & 15, c = tid >> 4;
    const int o = blockIdx.x * 16 + oLoc;
    const int b0 = c * 68;
    const int bN = (NB2 - b0 < 68) ? (NB2 - b0) : 68;
    const float* p = part + (long)b0 * PSZ + o;
    float s = 0.f;
    #pragma unroll 4
    for (int b = 0; b < bN; ++b) s += p[(long)b * PSZ];
    red[c][oLoc] = s;
    __syncthreads();
    if (tid < 16) {
        float t = 0.f;
        #pragma unroll
        for (int ci = 0; ci < 16; ++ci) t += red[ci][tid];
        out[blockIdx.x * 16 + tid] = t;
    }
}

__global__ __launch_bounds__(1024) void kB(
    const float* __restrict__ alphaAcc, const int* __restrict__ label,
    const float* __restrict__ Wfvb, const float* __restrict__ bfvb,
    const float* __restrict__ Wgvb, const float* __restrict__ bgvb,
    const float* __restrict__ Wfu,  const float* __restrict__ bfu,
    const float* __restrict__ Wgu,  const float* __restrict__ bgu,
    const float* __restrict__ Wfvc, const float* __restrict__ bfvc,
    float* __restrict__ uwb)
{
    __shared__ float up_l[N1 * H];
    __shared__ float un_l[N1 * H];
    __shared__ float cb_l[CC * H];
    __shared__ float cw_l[CC * H];
    __shared__ int   cnt[CC];
    const int tid = threadIdx.x;

    if (tid < CC) cnt[tid] = 0;
    __syncthreads();
    if (tid < N1) atomicAdd(&cnt[label[tid]], 1);
    __syncthreads();

    if (tid < CC * H) {
        const int c = tid / H, h = tid % H;
        const float nc = (float)cnt[c];
        float s = bgvb[h];
        #pragma unroll
        for (int k = 0; k < H; ++k) {
            const float t1c = (nc * fmaxf(Wfvb[k] + bfvb[k], 0.f) +
                               ((float)N1 - nc) * fmaxf(bfvb[k], 0.f)) * (1.f / N1);
            s = fmaf(t1c, Wgvb[k * H + h], s);
        }
        cb_l[tid] = fmaxf(s, 0.f);
    }
    __syncthreads();
    if (tid < CC * H) {
        const int c = tid / H, h = tid % H;
        float s = bfu[h];
        #pragma unroll
        for (int k = 0; k < H; ++k) s = fmaf(cb_l[c * H + k], Wfu[k * H + h], s);
        cw_l[tid] = s;
    }
    __syncthreads();
    for (int t = tid; t < N1 * H; t += 1024) {
        const int n = t >> 5, h = t & 31;
        const int ln = label[n];
        const float wud = Wfu[H * H + h];
        float s = 0.f;
        #pragma unroll
        for (int c = 0; c < CC; ++c)
            s += fmaxf(cw_l[c * H + h] + ((c == ln) ? wud : 0.f), 0.f);
        up_l[t] = alphaAcc[t] * (1.f / E_DIM) + s * (1.f / CC);
    }
    __syncthreads();
    for (int t = tid; t < N1 * H; t += 1024) {
        const int n = t >> 5, h = t & 31;
        float s = bgu[h];
        #pragma unroll
        for (int k = 0; k < H; ++k) s = fmaf(up_l[n * H + k], Wgu[k * H + h], s);
        un_l[t] = fmaxf(s, 0.f);
    }
    __syncthreads();
    for (int t = tid; t < N1 * H; t += 1024) {
        const int n = t >> 5, h = t & 31;
        float s = bfvc[h];
        #pragma unroll
        for (int k = 0; k < H; ++k) s = fmaf(un_l[n * H + k], Wfvc[k * H + h], s);
        uwb[t] = s;
    }
}

__global__ __launch_bounds__(1024) void kD(
    const float* __restrict__ zAcc,
    const float* __restrict__ Wgz, const float* __restrict__ bgz,
    float* __restrict__ out)
{
    __shared__ float z_l[N1 * H];
    const int tid = threadIdx.x;
    for (int t = tid; t < N1 * H; t += 1024) z_l[t] = zAcc[t] * (1.f / E_DIM);
    __syncthreads();
    for (int t = tid; t < N1 * H; t += 1024) {
        const int n = t >> 5, h = t & 31;
        float s = bgz[h];
        #pragma unroll
        for (int k = 0; k < H; ++k) s = fmaf(z_l[n * H + k], Wgz[k * H + h], s);
        out[t] = fmaxf(s, 0.f);
    }
}

extern "C" void kernel_launch(void* const* d_in, const int* in_sizes, int n_in,
                              void* d_out, int out_size, void* d_ws, size_t ws_size,
                              hipStream_t stream)
{
    const float* sup  = (const float*)d_in[0];
    const int*   lab  = (const int*)d_in[1];
    const float* qry  = (const float*)d_in[2];
    const float* Wfvb = (const float*)d_in[3];
    const float* bfvb = (const float*)d_in[4];
    const float* Wgvb = (const float*)d_in[5];
    const float* bgvb = (const float*)d_in[6];
    const float* Wfu  = (const float*)d_in[7];
    const float* bfu  = (const float*)d_in[8];
    const float* Wgu  = (const float*)d_in[9];
    const float* bgu  = (const float*)d_in[10];
    const float* Wfvc = (const float*)d_in[11];
    const float* bfvc = (const float*)d_in[12];
    const float* Wgvc = (const float*)d_in[13];
    const float* bgvc = (const float*)d_in[14];
    const float* Wfz  = (const float*)d_in[15];
    const float* bfz  = (const float*)d_in[16];
    const float* Wgz  = (const float*)d_in[17];
    const float* bgz  = (const float*)d_in[18];
    float* out = (float*)d_out;

    float* alphaAcc = (float*)d_ws;
    float* zAcc     = alphaAcc + PSZ;
    float* uwb      = zAcc + PSZ;
    float* partA    = uwb + PSZ;
    float* partZ    = partA + (size_t)NB2 * PSZ;

    const size_t needMain = (3 * (size_t)PSZ + 2 * (size_t)NB2 * PSZ) * sizeof(float);

    if (ws_size >= needMain) {
        kA19<false><<<NB2, 512, 0, stream>>>(sup, Wfvb, bfvb, Wgvb, bgvb, Wfu, bfu, partA);
        kR<<<PSZ / 16, 256, 0, stream>>>(partA, alphaAcc);
        kB<<<1, 1024, 0, stream>>>(alphaAcc, lab, Wfvb, bfvb, Wgvb, bgvb, Wfu, bfu,
                                   Wgu, bgu, Wfvc, bfvc, uwb);
        kCf21<false><<<NB2, 512, 0, stream>>>(sup, qry, uwb, Wfvc, Wgvc, bgvc, Wfz, bfz, partZ);
        kR<<<PSZ / 16, 256, 0, stream>>>(partZ, zAcc);
        kD<<<1, 1024, 0, stream>>>(zAcc, Wgz, bgz, out);
    } else {
        (void)hipMemsetAsync(alphaAcc, 0, 2 * PSZ * sizeof(float), stream);
        kA19<true><<<NB2, 512, 0, stream>>>(sup, Wfvb, bfvb, Wgvb, bgvb, Wfu, bfu, alphaAcc);
        kB<<<1, 1024, 0, stream>>>(alphaAcc, lab, Wfvb, bfvb, Wgvb, bgvb, Wfu, bfu,
                                   Wgu, bgu, Wfvc, bfvc, uwb);
        kCf21<true><<<NB2, 512, 0, stream>>>(sup, qry, uwb, Wfvc, Wgvc, bgvc, Wfz, bfz, zAcc);
        kD<<<1, 1024, 0, stream>>>(zAcc, Wgz, bgz, out);
    }
}

// Round 15
// 85.505 us; speedup vs baseline: 3.0269x; 1.0514x over previous
//
#include <hip/hip_runtime.h>

#define E_DIM 69120
#define N1 60
#define H 32
#define CC 3
#define TEB 64
#define NB2 (E_DIM / TEB)   // 1080
#define SDS 68              // d-tile stride (floats); rows 16B-aligned
#define SBA 34              // chain buffer stride
#define SBT 68              // bufT stride (16B-aligned rows for b128)
#define PSZ (N1 * H)        // 1920

typedef float f2 __attribute__((ext_vector_type(2)));

__device__ __forceinline__ f2 relu_fma2(f2 a, f2 b, f2 c) {
    return __builtin_elementwise_max(__builtin_elementwise_fma(a, b, c), (f2)(0.f));
}

// LDS: ds[60*68]=4080f | bufA[64*34]=2176f (bufT[32][68] overlay)
//      | bufB[64*34]=2176f (u_l overlay in kCf) -> 33,728 B -> 4 blocks/CU

// =====================================================================
// kA23: v_bar chain + alpha partials (packed fp32 math).
// ph1-3: (eL 0..63, hg 0..7 -> 4h).  ph4: wave r owns n in [8r, 8r+8),
// lane = (nq2 0..1 -> 4n, hl 0..31 -> 1h): broadcast reads.
// =====================================================================
template<bool ATOMIC>
__global__ __launch_bounds__(512, 4) void kA23(
    const float* __restrict__ d,
    const float* __restrict__ Wfvb, const float* __restrict__ bfvb,
    const float* __restrict__ Wgvb, const float* __restrict__ bgvb,
    const float* __restrict__ Wfu,  const float* __restrict__ bfu,
    float* __restrict__ outp)
{
    __shared__ __align__(16) float ds[N1 * SDS];
    __shared__ __align__(16) float bufA[64 * SBA];
    __shared__ __align__(16) float bufB[64 * SBA];
    float* bufT = bufA;   // [32][SBT] overlay after bufA dead
    const int tid = threadIdx.x;
    const long sE = (long)blockIdx.x * TEB;

    // ph0: stage support tile
    for (int i = tid; i < N1 * (TEB / 4); i += 512) {
        const int n = i >> 4, c = (i & 15) * 4;
        *(float4*)(ds + n * SDS + c) = *(const float4*)(d + (long)n * E_DIM + sE + c);
    }
    __syncthreads();

    const int eL = tid & 63;
    const int h0 = __builtin_amdgcn_readfirstlane((tid >> 6) * 4);

    // ph1: t1 = mean_n relu(d*wf + bf); packed, dual-n; 1/N1 folded
    {
        f2 wf[2], bf[2], ta[2], tb[2];
        #pragma unroll
        for (int q = 0; q < 2; ++q) {
            wf[q] = f2{Wfvb[h0 + 2*q] * (1.f/N1), Wfvb[h0 + 2*q + 1] * (1.f/N1)};
            bf[q] = f2{bfvb[h0 + 2*q] * (1.f/N1), bfvb[h0 + 2*q + 1] * (1.f/N1)};
            ta[q] = (f2)(0.f); tb[q] = (f2)(0.f);
        }
        const float* dp = ds + eL;
        #pragma unroll 5
        for (int n = 0; n < N1; n += 2) {
            const float dv0 = dp[n * SDS];
            const float dv1 = dp[(n + 1) * SDS];
            const f2 d02 = f2{dv0, dv0}, d12 = f2{dv1, dv1};
            #pragma unroll
            for (int q = 0; q < 2; ++q) {
                ta[q] += relu_fma2(d02, wf[q], bf[q]);
                tb[q] += relu_fma2(d12, wf[q], bf[q]);
            }
        }
        #pragma unroll
        for (int q = 0; q < 2; ++q)
            *(f2*)(bufA + eL * SBA + h0 + 2*q) = ta[q] + tb[q];
    }
    __syncthreads();

    // ph2: vb = relu(t1 @ Wgvb + bgvb) -> bufB (packed)
    {
        f2 acc[2];
        #pragma unroll
        for (int q = 0; q < 2; ++q) acc[q] = f2{bgvb[h0 + 2*q], bgvb[h0 + 2*q + 1]};
        #pragma unroll
        for (int k = 0; k < H; ++k) {
            const float t = bufA[eL * SBA + k];
            const f2 t2 = f2{t, t};
            #pragma unroll
            for (int q = 0; q < 2; ++q)
                acc[q] = __builtin_elementwise_fma(t2, *(const f2*)(Wgvb + k * H + h0 + 2*q), acc[q]);
        }
        #pragma unroll
        for (int q = 0; q < 2; ++q)
            *(f2*)(bufB + eL * SBA + h0 + 2*q) = __builtin_elementwise_max(acc[q], (f2)(0.f));
    }
    __syncthreads();

    // ph3: vw = vb @ Wu_v + b_fu -> bufT (transposed; bufA dead)
    {
        f2 acc[2];
        #pragma unroll
        for (int q = 0; q < 2; ++q) acc[q] = f2{bfu[h0 + 2*q], bfu[h0 + 2*q + 1]};
        #pragma unroll
        for (int k = 0; k < H; ++k) {
            const float t = bufB[eL * SBA + k];
            const f2 t2 = f2{t, t};
            #pragma unroll
            for (int q = 0; q < 2; ++q)
                acc[q] = __builtin_elementwise_fma(t2, *(const f2*)(Wfu + k * H + h0 + 2*q), acc[q]);
        }
        #pragma unroll
        for (int q = 0; q < 2; ++q) {
            bufT[(h0 + 2*q)     * SBT + eL] = acc[q].x;
            bufT[(h0 + 2*q + 1) * SBT + eL] = acc[q].y;
        }
    }
    __syncthreads();

    // ph4: alpha partials. wave r: n in [8r,8r+8); lane: nq2 (4 n's), hl (1 h).
    {
        const int hl = tid & 31;
        const int bn = ((tid >> 6) << 3) + ((tid >> 5) & 1) * 4;
        if (bn < N1) {
            const float wv = Wfu[H * H + hl];
            const f2 wv2 = f2{wv, wv};
            f2 acc2[4];
            #pragma unroll
            for (int i = 0; i < 4; ++i) acc2[i] = (f2)(0.f);
            const float* dr = ds + bn * SDS;
            #pragma unroll 2
            for (int e4 = 0; e4 < TEB; e4 += 4) {
                const float4 w4 = *(const float4*)(bufT + hl * SBT + e4);
                const f2 wa = f2{w4.x, w4.y}, wb = f2{w4.z, w4.w};
                #pragma unroll
                for (int i = 0; i < 4; ++i) {
                    const float4 di = *(const float4*)(dr + i * SDS + e4);
                    acc2[i] += relu_fma2(f2{di.x, di.y}, wv2, wa)
                             + relu_fma2(f2{di.z, di.w}, wv2, wb);
                }
            }
            if (ATOMIC) {
                #pragma unroll
                for (int i = 0; i < 4; ++i) atomicAdd(&outp[(bn + i) * H + hl], acc2[i].x + acc2[i].y);
            } else {
                float* base = outp + (long)blockIdx.x * PSZ;
                #pragma unroll
                for (int i = 0; i < 4; ++i) base[(bn + i) * H + hl] = acc2[i].x + acc2[i].y;
            }
        }
    }
}

// =====================================================================
// kCf23: fused v-chain + z partials (packed). Query tile staged into
// ds (dead after ph1); loads issued after B1, hidden under ph2.
// =====================================================================
template<bool ATOMIC>
__global__ __launch_bounds__(512, 4) void kCf23(
    const float* __restrict__ d, const float* __restrict__ d2,
    const float* __restrict__ uwb,
    const float* __restrict__ Wfvc,
    const float* __restrict__ Wgvc, const float* __restrict__ bgvc,
    const float* __restrict__ Wfz,  const float* __restrict__ bfz,
    float* __restrict__ outp)
{
    __shared__ __align__(16) float ds[N1 * SDS];
    __shared__ __align__(16) float bufA[64 * SBA];
    __shared__ __align__(16) float bufB[64 * SBA];
    float* bufT = bufA;
    float* u_l  = bufB;   // [60][32] overlay: read in ph1, dead before ph2 writes
    const int tid = threadIdx.x;
    const long sE = (long)blockIdx.x * TEB;

    // ph0: stage support tile + uwb (pre-scaled by 1/N1)
    for (int i = tid; i < N1 * (TEB / 4); i += 512) {
        const int n = i >> 4, c = (i & 15) * 4;
        *(float4*)(ds + n * SDS + c) = *(const float4*)(d + (long)n * E_DIM + sE + c);
    }
    if (tid < PSZ / 4) {
        float4 u = ((const float4*)uwb)[tid];
        u.x *= (1.f / N1); u.y *= (1.f / N1); u.z *= (1.f / N1); u.w *= (1.f / N1);
        ((float4*)u_l)[tid] = u;
    }
    __syncthreads();

    const int eL = tid & 63;
    const int h0 = __builtin_amdgcn_readfirstlane((tid >> 6) * 4);

    // ph1: m = mean_n relu(d*wvd + u); packed, dual-n
    {
        f2 wvd[2], ma[2], mb[2];
        #pragma unroll
        for (int q = 0; q < 2; ++q) {
            wvd[q] = f2{Wfvc[H * H + h0 + 2*q] * (1.f/N1), Wfvc[H * H + h0 + 2*q + 1] * (1.f/N1)};
            ma[q] = (f2)(0.f); mb[q] = (f2)(0.f);
        }
        const float* dp = ds + eL;
        #pragma unroll 5
        for (int n = 0; n < N1; n += 2) {
            const float dv0 = dp[n * SDS];
            const float dv1 = dp[(n + 1) * SDS];
            const f2 d02 = f2{dv0, dv0}, d12 = f2{dv1, dv1};
            #pragma unroll
            for (int q = 0; q < 2; ++q) {
                const f2 u0 = *(const f2*)(u_l + n * H + h0 + 2*q);        // broadcast
                const f2 u1 = *(const f2*)(u_l + (n + 1) * H + h0 + 2*q);  // broadcast
                ma[q] += relu_fma2(d02, wvd[q], u0);
                mb[q] += relu_fma2(d12, wvd[q], u1);
            }
        }
        #pragma unroll
        for (int q = 0; q < 2; ++q)
            *(f2*)(bufA + eL * SBA + h0 + 2*q) = ma[q] + mb[q];
    }
    __syncthreads();   // B1: bufA ready; ds (support) now DEAD

    // issue query-tile loads early; HBM latency hides under ph2
    float4 q0, q1;
    {
        const int n0 = tid >> 4, c0 = (tid & 15) * 4;
        q0 = *(const float4*)(d2 + (long)n0 * E_DIM + sE + c0);
        if (tid < 448) {
            const int i1 = tid + 512, n1 = i1 >> 4, c1 = (i1 & 15) * 4;
            q1 = *(const float4*)(d2 + (long)n1 * E_DIM + sE + c1);
        }
    }

    // ph2: v = relu(m @ Wgvc + bgvc) -> bufB (u_l dead)
    {
        f2 acc[2];
        #pragma unroll
        for (int q = 0; q < 2; ++q) acc[q] = f2{bgvc[h0 + 2*q], bgvc[h0 + 2*q + 1]};
        #pragma unroll
        for (int k = 0; k < H; ++k) {
            const float t = bufA[eL * SBA + k];
            const f2 t2 = f2{t, t};
            #pragma unroll
            for (int q = 0; q < 2; ++q)
                acc[q] = __builtin_elementwise_fma(t2, *(const f2*)(Wgvc + k * H + h0 + 2*q), acc[q]);
        }
        #pragma unroll
        for (int q = 0; q < 2; ++q)
            *(f2*)(bufB + eL * SBA + h0 + 2*q) = __builtin_elementwise_max(acc[q], (f2)(0.f));
    }

    // write query tile into ds (support dead since B1)
    {
        const int n0 = tid >> 4, c0 = (tid & 15) * 4;
        *(float4*)(ds + n0 * SDS + c0) = q0;
        if (tid < 448) {
            const int i1 = tid + 512, n1 = i1 >> 4, c1 = (i1 & 15) * 4;
            *(float4*)(ds + n1 * SDS + c1) = q1;
        }
    }
    __syncthreads();   // B2: bufB + query tile ready

    // ph3: vz = v @ Wz_v + b_fz -> bufT (bufA dead)
    {
        f2 acc[2];
        #pragma unroll
        for (int q = 0; q < 2; ++q) acc[q] = f2{bfz[h0 + 2*q], bfz[h0 + 2*q + 1]};
        #pragma unroll
        for (int k = 0; k < H; ++k) {
            const float t = bufB[eL * SBA + k];
            const f2 t2 = f2{t, t};
            #pragma unroll
            for (int q = 0; q < 2; ++q)
                acc[q] = __builtin_elementwise_fma(t2, *(const f2*)(Wfz + k * H + h0 + 2*q), acc[q]);
        }
        #pragma unroll
        for (int q = 0; q < 2; ++q) {
            bufT[(h0 + 2*q)     * SBT + eL] = acc[q].x;
            bufT[(h0 + 2*q + 1) * SBT + eL] = acc[q].y;
        }
    }
    __syncthreads();   // B3: bufT ready

    // ph4: z partials. wave r: n in [8r,8r+8); query rows from LDS.
    {
        const int hl = tid & 31;
        const int bn = ((tid >> 6) << 3) + ((tid >> 5) & 1) * 4;
        if (bn < N1) {
            const float wv = Wfz[H * H + hl];
            const f2 wv2 = f2{wv, wv};
            f2 acc2[4];
            #pragma unroll
            for (int i = 0; i < 4; ++i) acc2[i] = (f2)(0.f);
            const float* dr = ds + bn * SDS;
            #pragma unroll 2
            for (int e4 = 0; e4 < TEB; e4 += 4) {
                const float4 w4 = *(const float4*)(bufT + hl * SBT + e4);
                const f2 wa = f2{w4.x, w4.y}, wb = f2{w4.z, w4.w};
                #pragma unroll
                for (int i = 0; i < 4; ++i) {
                    const float4 di = *(const float4*)(dr + i * SDS + e4);
                    acc2[i] += relu_fma2(f2{di.x, di.y}, wv2, wa)
                             + relu_fma2(f2{di.z, di.w}, wv2, wb);
                }
            }
            if (ATOMIC) {
                #pragma unroll
                for (int i = 0; i < 4; ++i) atomicAdd(&outp[(bn + i) * H + hl], acc2[i].x + acc2[i].y);
            } else {
                float* base = outp + (long)blockIdx.x * PSZ;
                #pragma unroll
                for (int i = 0; i < 4; ++i) base[(bn + i) * H + hl] = acc2[i].x + acc2[i].y;
            }
        }
    }
}

// reduce part[NB2][PSZ] -> out[PSZ]; grid = PSZ/16 = 120 blocks
__global__ __launch_bounds__(256) void kR(
    const float* __restrict__ part, float* __restrict__ out)
{
    __shared__ float red[16][17];
    const int tid = threadIdx.x;
    const int oLoc = tid & 15, c = tid >> 4;
    const int o = blockIdx.x * 16 + oLoc;
    const int b0 = c * 68;
    const int bN = (NB2 - b0 < 68) ? (NB2 - b0) : 68;
    const float* p = part + (long)b0 * PSZ + o;
    float s = 0.f;
    #pragma unroll 4
    for (int b = 0; b < bN; ++b) s += p[(long)b * PSZ];
    red[c][oLoc] = s;
    __syncthreads();
    if (tid < 16) {
        float t = 0.f;
        #pragma unroll
        for (int ci = 0; ci < 16; ++ci) t += red[ci][tid];
        out[blockIdx.x * 16 + tid] = t;
    }
}

__global__ __launch_bounds__(1024) void kB(
    const float* __restrict__ alphaAcc, const int* __restrict__ label,
    const float* __restrict__ Wfvb, const float* __restrict__ bfvb,
    const float* __restrict__ Wgvb, const float* __restrict__ bgvb,
    const float* __restrict__ Wfu,  const float* __restrict__ bfu,
    const float* __restrict__ Wgu,  const float* __restrict__ bgu,
    const float* __restrict__ Wfvc, const float* __restrict__ bfvc,
    float* __restrict__ uwb)
{
    __shared__ float up_l[N1 * H];
    __shared__ float un_l[N1 * H];
    __shared__ float cb_l[CC * H];
    __shared__ float cw_l[CC * H];
    __shared__ int   cnt[CC];
    const int tid = threadIdx.x;

    if (tid < CC) cnt[tid] = 0;
    __syncthreads();
    if (tid < N1) atomicAdd(&cnt[label[tid]], 1);
    __syncthreads();

    if (tid < CC * H) {
        const int c = tid / H, h = tid % H;
        const float nc = (float)cnt[c];
        float s = bgvb[h];
        #pragma unroll
        for (int k = 0; k < H; ++k) {
            const float t1c = (nc * fmaxf(Wfvb[k] + bfvb[k], 0.f) +
                               ((float)N1 - nc) * fmaxf(bfvb[k], 0.f)) * (1.f / N1);
            s = fmaf(t1c, Wgvb[k * H + h], s);
        }
        cb_l[tid] = fmaxf(s, 0.f);
    }
    __syncthreads();
    if (tid < CC * H) {
        const int c = tid / H, h = tid % H;
        float s = bfu[h];
        #pragma unroll
        for (int k = 0; k < H; ++k) s = fmaf(cb_l[c * H + k], Wfu[k * H + h], s);
        cw_l[tid] = s;
    }
    __syncthreads();
    for (int t = tid; t < N1 * H; t += 1024) {
        const int n = t >> 5, h = t & 31;
        const int ln = label[n];
        const float wud = Wfu[H * H + h];
        float s = 0.f;
        #pragma unroll
        for (int c = 0; c < CC; ++c)
            s += fmaxf(cw_l[c * H + h] + ((c == ln) ? wud : 0.f), 0.f);
        up_l[t] = alphaAcc[t] * (1.f / E_DIM) + s * (1.f / CC);
    }
    __syncthreads();
    for (int t = tid; t < N1 * H; t += 1024) {
        const int n = t >> 5, h = t & 31;
        float s = bgu[h];
        #pragma unroll
        for (int k = 0; k < H; ++k) s = fmaf(up_l[n * H + k], Wgu[k * H + h], s);
        un_l[t] = fmaxf(s, 0.f);
    }
    __syncthreads();
    for (int t = tid; t < N1 * H; t += 1024) {
        const int n = t >> 5, h = t & 31;
        float s = bfvc[h];
        #pragma unroll
        for (int k = 0; k < H; ++k) s = fmaf(un_l[n * H + k], Wfvc[k * H + h], s);
        uwb[t] = s;
    }
}

__global__ __launch_bounds__(1024) void kD(
    const float* __restrict__ zAcc,
    const float* __restrict__ Wgz, const float* __restrict__ bgz,
    float* __restrict__ out)
{
    __shared__ float z_l[N1 * H];
    const int tid = threadIdx.x;
    for (int t = tid; t < N1 * H; t += 1024) z_l[t] = zAcc[t] * (1.f / E_DIM);
    __syncthreads();
    for (int t = tid; t < N1 * H; t += 1024) {
        const int n = t >> 5, h = t & 31;
        float s = bgz[h];
        #pragma unroll
        for (int k = 0; k < H; ++k) s = fmaf(z_l[n * H + k], Wgz[k * H + h], s);
        out[t] = fmaxf(s, 0.f);
    }
}

extern "C" void kernel_launch(void* const* d_in, const int* in_sizes, int n_in,
                              void* d_out, int out_size, void* d_ws, size_t ws_size,
                              hipStream_t stream)
{
    const float* sup  = (const float*)d_in[0];
    const int*   lab  = (const int*)d_in[1];
    const float* qry  = (const float*)d_in[2];
    const float* Wfvb = (const float*)d_in[3];
    const float* bfvb = (const float*)d_in[4];
    const float* Wgvb = (const float*)d_in[5];
    const float* bgvb = (const float*)d_in[6];
    const float* Wfu  = (const float*)d_in[7];
    const float* bfu  = (const float*)d_in[8];
    const float* Wgu  = (const float*)d_in[9];
    const float* bgu  = (const float*)d_in[10];
    const float* Wfvc = (const float*)d_in[11];
    const float* bfvc = (const float*)d_in[12];
    const float* Wgvc = (const float*)d_in[13];
    const float* bgvc = (const float*)d_in[14];
    const float* Wfz  = (const float*)d_in[15];
    const float* bfz  = (const float*)d_in[16];
    const float* Wgz  = (const float*)d_in[17];
    const float* bgz  = (const float*)d_in[18];
    float* out = (float*)d_out;

    float* alphaAcc = (float*)d_ws;
    float* zAcc     = alphaAcc + PSZ;
    float* uwb      = zAcc + PSZ;
    float* partA    = uwb + PSZ;
    float* partZ    = partA + (size_t)NB2 * PSZ;

    const size_t needMain = (3 * (size_t)PSZ + 2 * (size_t)NB2 * PSZ) * sizeof(float);

    if (ws_size >= needMain) {
        kA23<false><<<NB2, 512, 0, stream>>>(sup, Wfvb, bfvb, Wgvb, bgvb, Wfu, bfu, partA);
        kR<<<PSZ / 16, 256, 0, stream>>>(partA, alphaAcc);
        kB<<<1, 1024, 0, stream>>>(alphaAcc, lab, Wfvb, bfvb, Wgvb, bgvb, Wfu, bfu,
                                   Wgu, bgu, Wfvc, bfvc, uwb);
        kCf23<false><<<NB2, 512, 0, stream>>>(sup, qry, uwb, Wfvc, Wgvc, bgvc, Wfz, bfz, partZ);
        kR<<<PSZ / 16, 256, 0, stream>>>(partZ, zAcc);
        kD<<<1, 1024, 0, stream>>>(zAcc, Wgz, bgz, out);
    } else {
        (void)hipMemsetAsync(alphaAcc, 0, 2 * PSZ * sizeof(float), stream);
        kA23<true><<<NB2, 512, 0, stream>>>(sup, Wfvb, bfvb, Wgvb, bgvb, Wfu, bfu, alphaAcc);
        kB<<<1, 1024, 0, stream>>>(alphaAcc, lab, Wfvb, bfvb, Wgvb, bgvb, Wfu, bfu,
                                   Wgu, bgu, Wfvc, bfvc, uwb);
        kCf23<true><<<NB2, 512, 0, stream>>>(sup, qry, uwb, Wfvc, Wgvc, bgvc, Wfz, bfz, zAcc);
        kD<<<1, 1024, 0, stream>>>(zAcc, Wgz, bgz, out);
    }
}